// Round 7
// baseline (339.908 us; speedup 1.0000x reference)
//
#include <hip/hip_runtime.h>
#include <hip/hip_bf16.h>

typedef unsigned short ushort_t;
typedef unsigned int uint_t;
typedef __attribute__((ext_vector_type(8))) short short8;
typedef __attribute__((ext_vector_type(4))) float f32x4;

#define EMBED 1024
#define RANK  512
#define BB    4
#define SS    4096
#define HH    16
#define DHD   64
#define MM    (BB*SS)   // 16384 rows
#define NCHUNK 16       // kv_stats n-parallelism (256 rows per chunk)

__device__ __forceinline__ float bf2f(ushort_t u) {
    union { uint_t i; float f; } v; v.i = ((uint_t)u) << 16; return v.f;
}
__device__ __forceinline__ ushort_t f2bf(float f) {
    union { float f; uint_t i; } v; v.f = f;
    uint_t r = v.i + 0x7FFFu + ((v.i >> 16) & 1u);   // RNE
    return (ushort_t)(r >> 16);
}
// async global->LDS, 16B per lane; LDS dest must be wave-uniform base (+lane*16 in HW)
__device__ __forceinline__ void gl2lds16(const void* g, void* l) {
    __builtin_amdgcn_global_load_lds((const __attribute__((address_space(1))) void*)g,
                                     (__attribute__((address_space(3))) void*)l,
                                     16, 0, 0);
}

// ---------------------------------------------------------------------------
// NT-GEMM: C[M,N] = A[M,K] * B[N,K]^T (+ epilogue). 256x128 tile, BK=32,
// 256 threads = 4 waves; wave w owns a 64x128 strip (rows w*64..w*64+63),
// acc[4][8] of 16x16 frags -> 32 MFMA per K-step per wave vs 12 ds_read_b128
// (0.375 b128/MFMA; the 128x128 tile was 0.5 — LDS read was co-critical).
// T4 counted-vmcnt pipeline: 3-deep LDS ring; prologue stages tiles 0,1;
// per iter: s_waitcnt vmcnt(6) (never 0 until last) -> raw s_barrier ->
// issue STAGE(ti+2) -> ds_read+MFMA. Loads span ~2 K-steps of MFMA.
// T2 LDS swizzle (both-sides, rule #21): rows are 64B = 4x16B slots;
// slot' = slot ^ ((row>>1)&3), applied via pre-swizzled GLOBAL source column
// (LDS dest stays linear for global_load_lds) and matching swizzled ds_read.
// (Consistency: all row bases are multiples of 16, so (row>>1)&3 depends
// only on fr / srow bits — staging and read sides agree.)
// Coalesced bf16 epilogue: C tile staged in LDS at stride 136 (row step
// 272B: 16B-aligned, banks spread), then short8 stores (256B contiguous per
// 16-lane group). fp32 (EPI 3) stores direct (full 64B sectors already).
// Up to 3 independent GEMMs per dispatch via blockIdx.z (same N,K).
// Bijective XCD swizzle: each XCD owns a contiguous run of row-panels.
// EPI: 0 = none (bf16), 2 = +bias, elu+1 for z<2 / bias for z==2 (bf16),
//      3 = +bias (fp32 out).
// ---------------------------------------------------------------------------
template<int EPI>
__global__ __launch_bounds__(256) void gemm_bt(
    const ushort_t* __restrict__ A0, const ushort_t* __restrict__ A1, const ushort_t* __restrict__ A2,
    const ushort_t* __restrict__ B0, const ushort_t* __restrict__ B1, const ushort_t* __restrict__ B2,
    const float* __restrict__ bias0, const float* __restrict__ bias1, const float* __restrict__ bias2,
    void* __restrict__ C0, void* __restrict__ C1, void* __restrict__ C2,
    int N, int K, int nbx)
{
    // LDS: A ring bufs 16KB @ 0/16K/32K; B ring bufs 8KB @ 48K/56K/64K.
    // Epilogue C tile (256x136 bf16 = 69.6KB) reuses the whole region.
    __shared__ __align__(16) char lds_raw[73728];

    const int z = blockIdx.z;
    const ushort_t* Ab   = (z == 0) ? A0 : (z == 1) ? A1 : A2;
    const ushort_t* Bm   = (z == 0) ? B0 : (z == 1) ? B1 : B2;
    const float*    bias = (z == 0) ? bias0 : (z == 1) ? bias1 : bias2;
    void*           Cv   = (z == 0) ? C0 : (z == 1) ? C1 : C2;

    // bijective XCD swizzle: XCD k owns wg in [k*cpx, (k+1)*cpx)
    const int cpx = gridDim.x >> 3;
    const int bid = blockIdx.x;
    const int wg  = (bid & 7) * cpx + (bid >> 3);
    const long m0 = (long)(wg / nbx) * 256;
    const long n0 = (long)(wg % nbx) * 128;

    const int t = threadIdx.x;
    const int lane = t & 63;
    const int w = t >> 6;
    const int wr = w * 64;            // wave's row strip
    const int fr = lane & 15;
    const int kq = (lane >> 4) * 8;

    // staging: thread t covers (row = t>>2, slot = t&3); global column is
    // PRE-SWIZZLED so the linear LDS write lands swizzled (rule #21).
    const int srow = t >> 2;          // 0..63
    const int scol = ((t & 3) ^ ((srow >> 1) & 3)) * 8;
    // fragment read: swizzled slot for this thread's (fr, kq) — loop-invariant
    const int kqs = (((kq >> 3) ^ ((fr >> 1) & 3))) * 8;

    auto STAGE = [&](int k0, int buf) {
        char* Ad = lds_raw + buf * 16384;
        char* Bd = lds_raw + 49152 + buf * 8192;
        #pragma unroll
        for (int p = 0; p < 4; ++p) {
            const int row = p * 64 + srow;
            gl2lds16(Ab + (m0 + row) * (long)K + k0 + scol, Ad + (p * 256 + w * 64) * 16);
        }
        #pragma unroll
        for (int p = 0; p < 2; ++p) {
            const int row = p * 64 + srow;
            gl2lds16(Bm + (n0 + row) * (long)K + k0 + scol, Bd + (p * 256 + w * 64) * 16);
        }
    };

    f32x4 acc[4][8] = {};
    const int nt = K >> 5;            // 16 or 32

    STAGE(0, 0);                      // 6 loads
    STAGE(32, 1);                     // 6 loads (12 outstanding)

    int cur = 0;
    for (int ti = 0; ti < nt; ++ti) {
        // wait for STAGE(ti): newest 6 (STAGE(ti+1)) may stay in flight
        if (ti + 1 < nt) { asm volatile("s_waitcnt vmcnt(6)" ::: "memory"); }
        else             { asm volatile("s_waitcnt vmcnt(0)" ::: "memory"); }
        __builtin_amdgcn_sched_barrier(0);
        __builtin_amdgcn_s_barrier();          // publish buf[cur] to all waves
        __builtin_amdgcn_sched_barrier(0);

        int nb = cur + 2; if (nb >= 3) nb -= 3;
        if (ti + 2 < nt) STAGE((ti + 2) << 5, nb);   // 2-deep lookahead

        const ushort_t* Asc = (const ushort_t*)(lds_raw + cur * 16384);
        const ushort_t* Bsc = (const ushort_t*)(lds_raw + 49152 + cur * 8192);
        short8 av[4], bv[8];
        #pragma unroll
        for (int mi = 0; mi < 4; ++mi)
            av[mi] = *(const short8*)&Asc[(wr + mi * 16 + fr) * 32 + kqs];
        #pragma unroll
        for (int nf = 0; nf < 8; ++nf)
            bv[nf] = *(const short8*)&Bsc[(nf * 16 + fr) * 32 + kqs];
        #pragma unroll
        for (int mi = 0; mi < 4; ++mi)
            #pragma unroll
            for (int nf = 0; nf < 8; ++nf)
                acc[mi][nf] = __builtin_amdgcn_mfma_f32_16x16x32_bf16(
                    av[mi], bv[nf], acc[mi][nf], 0, 0, 0);

        ++cur; if (cur == 3) cur = 0;
    }

    const int rj = (lane >> 4) * 4;
    if (EPI == 3) {
        // fp32 direct stores: 16 lanes x 4B = full 64B sectors already.
        float* Cf = (float*)Cv;
        __syncthreads();
        #pragma unroll
        for (int nf = 0; nf < 8; ++nf) {
            const long col = n0 + nf * 16 + fr;
            const float bval = bias[col];
            #pragma unroll
            for (int mi = 0; mi < 4; ++mi)
                #pragma unroll
                for (int j = 0; j < 4; ++j)
                    Cf[(m0 + wr + mi * 16 + rj + j) * (long)N + col] = acc[mi][nf][j] + bval;
        }
    } else {
        // bf16: stage in LDS (stride 136 shorts = 272B rows), coalesced stores.
        ushort_t* Ct = (ushort_t*)lds_raw;     // 256x136 bf16 = 69.6KB
        __syncthreads();                        // K-loop LDS fully retired
        const bool do_elu = (EPI == 2) && (z < 2);
        #pragma unroll
        for (int nf = 0; nf < 8; ++nf) {
            const int coll = nf * 16 + fr;
            const float bval = (EPI >= 2) ? bias[n0 + coll] : 0.0f;
            #pragma unroll
            for (int mi = 0; mi < 4; ++mi) {
                #pragma unroll
                for (int j = 0; j < 4; ++j) {
                    float x = acc[mi][nf][j];
                    if (EPI >= 2) x += bval;
                    if (do_elu) x = (x > 0.0f) ? (x + 1.0f) : __expf(x);
                    Ct[(wr + mi * 16 + rj + j) * 136 + coll] = f2bf(x);
                }
            }
        }
        __syncthreads();
        ushort_t* Cb = (ushort_t*)Cv;
        #pragma unroll
        for (int it = 0; it < 16; ++it) {
            const int idx = it * 256 + t;
            const int r   = idx >> 4;          // 0..255
            const int c8  = (idx & 15) * 8;    // 0..120
            short8 vv = *(const short8*)&Ct[r * 136 + c8];
            *(short8*)(Cb + (m0 + r) * (long)N + n0 + c8) = vv;
        }
    }
}

// ---------------------------------------------------------------------------
// Activation convert: fp32 -> bf16, 8 elems/thread. blockIdx.y picks q/k/v.
// ---------------------------------------------------------------------------
__global__ __launch_bounds__(256) void cvt_act(const float* __restrict__ q,
                                               const float* __restrict__ k,
                                               const float* __restrict__ v,
                                               ushort_t* __restrict__ qo,
                                               ushort_t* __restrict__ ko,
                                               ushort_t* __restrict__ vo)
{
    const int zz = blockIdx.y;
    const float* src = (zz == 0) ? q : (zz == 1) ? k : v;
    ushort_t*    dst = (zz == 0) ? qo : (zz == 1) ? ko : vo;
    const long i = ((long)blockIdx.x * 256 + threadIdx.x) * 8;
    f32x4 f0 = *(const f32x4*)(src + i);
    f32x4 f1 = *(const f32x4*)(src + i + 4);
    short8 h;
    h[0] = (short)f2bf(f0[0]); h[1] = (short)f2bf(f0[1]);
    h[2] = (short)f2bf(f0[2]); h[3] = (short)f2bf(f0[3]);
    h[4] = (short)f2bf(f1[0]); h[5] = (short)f2bf(f1[1]);
    h[6] = (short)f2bf(f1[2]); h[7] = (short)f2bf(f1[3]);
    *(short8*)(dst + i) = h;
}

// ---------------------------------------------------------------------------
// All 7 weight conversions in one dispatch. blockIdx.y selects the weight.
// ---------------------------------------------------------------------------
__global__ __launch_bounds__(256) void cvt_weights(
    const float* __restrict__ s0, const float* __restrict__ s1,
    const float* __restrict__ s2, const float* __restrict__ s3,
    const float* __restrict__ s4, const float* __restrict__ s5,
    const float* __restrict__ s6,
    ushort_t* __restrict__ d0, ushort_t* __restrict__ d1,
    ushort_t* __restrict__ d2, ushort_t* __restrict__ d3,
    ushort_t* __restrict__ d4, ushort_t* __restrict__ d5,
    ushort_t* __restrict__ d6)
{
    const int y = blockIdx.y;
    const float* src; ushort_t* dst; int n;
    switch (y) {
        case 0: src = s0; dst = d0; n = RANK * EMBED; break;
        case 1: src = s1; dst = d1; n = RANK * EMBED; break;
        case 2: src = s2; dst = d2; n = RANK * EMBED; break;
        case 3: src = s3; dst = d3; n = RANK * EMBED; break;
        case 4: src = s4; dst = d4; n = RANK * EMBED; break;
        case 5: src = s5; dst = d5; n = RANK * EMBED; break;
        default: src = s6; dst = d6; n = EMBED * EMBED; break;
    }
    const int i = (blockIdx.x * 256 + threadIdx.x) * 4;
    if (i < n) {
        f32x4 f = *(const f32x4*)(src + i);
        typedef __attribute__((ext_vector_type(4))) short short4v;
        short4v h;
        h[0] = (short)f2bf(f[0]); h[1] = (short)f2bf(f[1]);
        h[2] = (short)f2bf(f[2]); h[3] = (short)f2bf(f[3]);
        *(short4v*)(dst + i) = h;
    }
}

// ---------------------------------------------------------------------------
// Per-head partial stats over a 256-row n-chunk:
//   kvp[chunk][bh][e][d] = sum_n V[n,e]*K[n,d];  ksump[chunk][bh][d] = sum_n K[n,d]
// Grid: (64 bh, NCHUNK). 256 threads; thread owns 4 e x 4 d register tile.
// ---------------------------------------------------------------------------
__global__ __launch_bounds__(256) void kv_stats(const ushort_t* __restrict__ Kp,
                                                const ushort_t* __restrict__ Vp,
                                                float* __restrict__ kvp,
                                                float* __restrict__ ksump)
{
    __shared__ __align__(16) ushort_t Ks[64 * 64];
    __shared__ __align__(16) ushort_t Vs[64 * 64];
    const int t = threadIdx.x;
    const int w = t >> 6;
    const int bh = blockIdx.x;
    const int chunk = blockIdx.y;
    const int b = bh >> 4, h = bh & 15;
    const int d0 = (t & 15) * 4;
    const int e0 = (t >> 4) * 4;
    float acc[4][4] = {};
    float sks[4] = {};
    const long hbase = ((long)b * SS) * EMBED + h * DHD;

    for (int sub = 0; sub < 4; ++sub) {
        const int n00 = chunk * 256 + sub * 64;
        #pragma unroll
        for (int ro = 0; ro < 2; ++ro) {
            const int idx = ro * 256 + t;
            const int r = idx >> 3, c16 = idx & 7;
            const long g = hbase + (long)(n00 + r) * EMBED + c16 * 8;
            gl2lds16(Kp + g, (char*)Ks + (ro * 256 + w * 64) * 16);
            gl2lds16(Vp + g, (char*)Vs + (ro * 256 + w * 64) * 16);
        }
        __syncthreads();
        #pragma unroll 8
        for (int n = 0; n < 64; ++n) {
            const uint_t* kr = (const uint_t*)(Ks + n * 64 + d0);
            const uint_t* vr = (const uint_t*)(Vs + n * 64 + e0);
            const uint_t k01 = kr[0], k23 = kr[1];
            const uint_t v01 = vr[0], v23 = vr[1];
            float kd[4], ve[4];
            {
                union { uint_t i; float f; } a, bq, c, dq;
                a.i = k01 << 16; bq.i = k01 & 0xffff0000u;
                c.i = k23 << 16; dq.i = k23 & 0xffff0000u;
                kd[0] = a.f; kd[1] = bq.f; kd[2] = c.f; kd[3] = dq.f;
            }
            {
                union { uint_t i; float f; } a, bq, c, dq;
                a.i = v01 << 16; bq.i = v01 & 0xffff0000u;
                c.i = v23 << 16; dq.i = v23 & 0xffff0000u;
                ve[0] = a.f; ve[1] = bq.f; ve[2] = c.f; ve[3] = dq.f;
            }
            #pragma unroll
            for (int e = 0; e < 4; ++e)
                #pragma unroll
                for (int d = 0; d < 4; ++d)
                    acc[e][d] += ve[e] * kd[d];
            if (e0 == 0) {
                #pragma unroll
                for (int d = 0; d < 4; ++d) sks[d] += kd[d];
            }
        }
        __syncthreads();
    }

    float* dst = kvp + ((long)chunk * 64 + bh) * 4096;
    #pragma unroll
    for (int e = 0; e < 4; ++e) {
        f32x4 vv; vv[0] = acc[e][0]; vv[1] = acc[e][1]; vv[2] = acc[e][2]; vv[3] = acc[e][3];
        *(f32x4*)(dst + (e0 + e) * 64 + d0) = vv;
    }
    if (e0 == 0) {
        float* sd = ksump + ((long)chunk * 64 + bh) * 64 + d0;
        #pragma unroll
        for (int d = 0; d < 4; ++d) sd[d] = sks[d];
    }
}

// ---------------------------------------------------------------------------
// Reduce NCHUNK partials -> kvb (bf16) and ksumf (f32). Grid: 64 blocks.
// ---------------------------------------------------------------------------
__global__ __launch_bounds__(256) void kv_reduce(const float* __restrict__ kvp,
                                                 const float* __restrict__ ksump,
                                                 ushort_t* __restrict__ kvb,
                                                 float* __restrict__ ksumf)
{
    const int bh = blockIdx.x;
    const int t = threadIdx.x;
    const long base = (long)bh * 4096 + t * 16;
    f32x4 s[4] = {};
    #pragma unroll 4
    for (int c = 0; c < NCHUNK; ++c) {
        const float* src = kvp + (long)c * 64 * 4096 + base;
        #pragma unroll
        for (int j = 0; j < 4; ++j) s[j] += *(const f32x4*)(src + j * 4);
    }
    short8 o0, o1;
    #pragma unroll
    for (int j = 0; j < 4; ++j) {
        o0[j]     = (short)f2bf(s[0][j]); o0[4 + j] = (short)f2bf(s[1][j]);
        o1[j]     = (short)f2bf(s[2][j]); o1[4 + j] = (short)f2bf(s[3][j]);
    }
    *(short8*)(kvb + base)     = o0;
    *(short8*)(kvb + base + 8) = o1;

    if (t < 64) {
        float ss = 0.f;
        #pragma unroll
        for (int c = 0; c < NCHUNK; ++c) ss += ksump[(long)c * 64 * 64 + bh * 64 + t];
        ksumf[bh * 64 + t] = ss;
    }
}

// ---------------------------------------------------------------------------
// num = phi(q) @ kvT^T ; denom = phi(q) . ksum ; O = num/(denom+1e-6), bf16.
// Grid: (64 bh, 32 chunks of 128 rows). 4 waves, wave w owns rows w*32..+32.
// ---------------------------------------------------------------------------
__global__ __launch_bounds__(256) void attn_out(const ushort_t* __restrict__ Qp,
                                                const ushort_t* __restrict__ kvb,
                                                const float* __restrict__ ksum,
                                                ushort_t* __restrict__ Op)
{
    __shared__ __align__(16) ushort_t Qs[128 * 64];
    __shared__ __align__(16) ushort_t KVs[64 * 64];
    __shared__ float kss[64];
    __shared__ float dnm[128];
    const int t = threadIdx.x;
    const int w = t >> 6, lane = t & 63;
    const int bh = blockIdx.x, mc = blockIdx.y;
    const int b = bh >> 4, h = bh & 15;
    const long base = ((long)b * SS + mc * 128) * EMBED + h * DHD;

    #pragma unroll
    for (int ro = 0; ro < 4; ++ro) {
        const int idx = ro * 256 + t;
        const int r = idx >> 3, c16 = idx & 7;
        gl2lds16(Qp + base + (long)r * EMBED + c16 * 8,
                 (char*)Qs + (ro * 256 + w * 64) * 16);
    }
    #pragma unroll
    for (int ro = 0; ro < 2; ++ro) {
        const int idx = ro * 256 + t;
        gl2lds16(kvb + (long)bh * 4096 + idx * 8,
                 (char*)KVs + (ro * 256 + w * 64) * 16);
    }
    if (t < 64) kss[t] = ksum[bh * 64 + t];
    __syncthreads();

    if (t < 128) {   // denominator per row
        float s = 0.f;
        const uint_t* qr = (const uint_t*)(Qs + t * 64);
        #pragma unroll
        for (int jj = 0; jj < 32; ++jj) {
            const uint_t u = qr[jj];
            union { uint_t i; float f; } lo, hi;
            lo.i = u << 16; hi.i = u & 0xffff0000u;
            s += lo.f * kss[2 * jj] + hi.f * kss[2 * jj + 1];
        }
        dnm[t] = s;
    }

    const int fr = lane & 15, kq = (lane >> 4) * 8;
    f32x4 acc[2][4] = {};
    #pragma unroll
    for (int ks = 0; ks < 2; ++ks) {
        short8 av[2], bv[4];
        #pragma unroll
        for (int mi = 0; mi < 2; ++mi)
            av[mi] = *(const short8*)&Qs[(w * 32 + mi * 16 + fr) * 64 + ks * 32 + kq];
        #pragma unroll
        for (int nf = 0; nf < 4; ++nf)
            bv[nf] = *(const short8*)&KVs[(nf * 16 + fr) * 64 + ks * 32 + kq];
        #pragma unroll
        for (int mi = 0; mi < 2; ++mi)
            #pragma unroll
            for (int nf = 0; nf < 4; ++nf)
                acc[mi][nf] = __builtin_amdgcn_mfma_f32_16x16x32_bf16(
                    av[mi], bv[nf], acc[mi][nf], 0, 0, 0);
    }
    __syncthreads();

    const int rj = (lane >> 4) * 4;
    #pragma unroll
    for (int mi = 0; mi < 2; ++mi) {
        #pragma unroll
        for (int nf = 0; nf < 4; ++nf) {
            #pragma unroll
            for (int j = 0; j < 4; ++j) {
                const int r = w * 32 + mi * 16 + rj + j;
                const int c = nf * 16 + fr;
                const float x = acc[mi][nf][j] / (dnm[r] + 1e-6f);
                Op[base + (long)r * EMBED + c] = f2bf(x);
            }
        }
    }
}

// ---------------------------------------------------------------------------
extern "C" void kernel_launch(void* const* d_in, const int* in_sizes, int n_in,
                              void* d_out, int out_size, void* d_ws, size_t ws_size,
                              hipStream_t stream)
{
    (void)in_sizes; (void)n_in; (void)out_size; (void)ws_size;
    const float* query = (const float*)d_in[0];
    const float* key_  = (const float*)d_in[1];
    const float* value = (const float*)d_in[2];
    const float* q_dw  = (const float*)d_in[3];
    const float* q_uw  = (const float*)d_in[4];
    const float* q_ub  = (const float*)d_in[5];
    const float* k_dw  = (const float*)d_in[6];
    const float* k_uw  = (const float*)d_in[7];
    const float* k_ub  = (const float*)d_in[8];
    const float* v_dw  = (const float*)d_in[9];
    const float* v_uw  = (const float*)d_in[10];
    const float* v_ub  = (const float*)d_in[11];
    const float* o_w   = (const float*)d_in[12];
    const float* o_b   = (const float*)d_in[13];

    char* ws = (char*)d_ws;
    size_t off = 0;
    auto alloc = [&](size_t bytes) -> void* {
        void* p = ws + off;
        off += (bytes + 255) & ~(size_t)255;
        return p;
    };
    const size_t WSMALL = (size_t)RANK * EMBED;   // 524288
    ushort_t* bw_qd = (ushort_t*)alloc(WSMALL * 2);
    ushort_t* bw_qu = (ushort_t*)alloc(WSMALL * 2);
    ushort_t* bw_kd = (ushort_t*)alloc(WSMALL * 2);
    ushort_t* bw_ku = (ushort_t*)alloc(WSMALL * 2);
    ushort_t* bw_vd = (ushort_t*)alloc(WSMALL * 2);
    ushort_t* bw_vu = (ushort_t*)alloc(WSMALL * 2);
    ushort_t* bw_o  = (ushort_t*)alloc((size_t)EMBED * EMBED * 2);
    ushort_t* Qb    = (ushort_t*)alloc((size_t)MM * EMBED * 2);   // 33.55 MB
    ushort_t* Kb    = (ushort_t*)alloc((size_t)MM * EMBED * 2);
    ushort_t* Vb    = (ushort_t*)alloc((size_t)MM * EMBED * 2);
    ushort_t* Y1q   = (ushort_t*)alloc((size_t)MM * RANK * 2);    // 16.78 MB
    ushort_t* Y1k   = (ushort_t*)alloc((size_t)MM * RANK * 2);
    ushort_t* Y1v   = (ushort_t*)alloc((size_t)MM * RANK * 2);
    float*    ksump = (float*)alloc((size_t)NCHUNK * 64 * 64 * 4);
    float*    ksumf = (float*)alloc((size_t)64 * 64 * 4);
    ushort_t* kvb   = (ushort_t*)alloc((size_t)64 * 64 * 64 * 2);

    // Aliases (lifetime-disjoint):
    //  PQ/PK/PV reuse Qb/Kb/Vb (dead after down-proj).
    //  kvp (NCHUNK*64*4096*4 = 16,777,216 B) reuses Y1q (dead after up-proj).
    //  O (33.55 MB) reuses Y1k+Y1v (contiguous 2x16,777,216 B, 256-aligned).
    ushort_t* PQ = Qb;
    ushort_t* PK = Kb;
    ushort_t* PV = Vb;
    float*    kvp = (float*)Y1q;
    ushort_t* O   = Y1k;

    const dim3 blk(256);

    // converts: QKV activations (8 elems/thread) + 7 weights
    cvt_act<<<dim3((size_t)MM * EMBED / 2048, 3), blk, 0, stream>>>(
        query, key_, value, Qb, Kb, Vb);
    cvt_weights<<<dim3(EMBED * EMBED / 1024, 7), blk, 0, stream>>>(
        q_dw, q_uw, k_dw, k_uw, v_dw, v_uw, o_w,
        bw_qd, bw_qu, bw_kd, bw_ku, bw_vd, bw_vu, bw_o);

    // 3 down-projections in one dispatch (pure bf16), 256x128 tiles
    gemm_bt<0><<<dim3(MM / 256 * (RANK / 128), 1, 3), blk, 0, stream>>>(
        Qb, Kb, Vb,
        bw_qd, bw_kd, bw_vd,
        nullptr, nullptr, nullptr,
        Y1q, Y1k, Y1v,
        RANK, EMBED, RANK / 128);

    // 3 up-projections: z=0 q (elu+1), z=1 k (elu+1), z=2 v (bias only)
    gemm_bt<2><<<dim3(MM / 256 * (EMBED / 128), 1, 3), blk, 0, stream>>>(
        Y1q, Y1k, Y1v,
        bw_qu, bw_ku, bw_vu,
        q_ub, k_ub, v_ub,
        PQ, PK, PV,
        EMBED, RANK, EMBED / 128);

    kv_stats<<<dim3(64, NCHUNK), blk, 0, stream>>>(PK, PV, kvp, ksump);
    kv_reduce<<<dim3(64), blk, 0, stream>>>(kvp, ksump, kvb, ksumf);
    attn_out<<<dim3(64, 32), blk, 0, stream>>>(PQ, kvb, ksumf, O);

    // output projection (fp32 out)
    gemm_bt<3><<<dim3(MM / 256 * (EMBED / 128), 1, 1), blk, 0, stream>>>(
        O, nullptr, nullptr,
        bw_o, nullptr, nullptr,
        o_b, nullptr, nullptr,
        d_out, nullptr, nullptr,
        EMBED, EMBED, EMBED / 128);
}

// Round 8
// 318.874 us; speedup vs baseline: 1.0660x; 1.0660x over previous
//
#include <hip/hip_runtime.h>
#include <hip/hip_bf16.h>

typedef unsigned short ushort_t;
typedef unsigned int uint_t;
typedef __attribute__((ext_vector_type(8))) short short8;
typedef __attribute__((ext_vector_type(4))) float f32x4;

#define EMBED 1024
#define RANK  512
#define BB    4
#define SS    4096
#define HH    16
#define DHD   64
#define MM    (BB*SS)   // 16384 rows
#define NCHUNK 16       // kv_stats n-parallelism (256 rows per chunk)

__device__ __forceinline__ float bf2f(ushort_t u) {
    union { uint_t i; float f; } v; v.i = ((uint_t)u) << 16; return v.f;
}
__device__ __forceinline__ ushort_t f2bf(float f) {
    union { float f; uint_t i; } v; v.f = f;
    uint_t r = v.i + 0x7FFFu + ((v.i >> 16) & 1u);   // RNE
    return (ushort_t)(r >> 16);
}
// async global->LDS, 16B per lane; LDS dest must be wave-uniform base (+lane*16 in HW)
__device__ __forceinline__ void gl2lds16(const void* g, void* l) {
    __builtin_amdgcn_global_load_lds((const __attribute__((address_space(1))) void*)g,
                                     (__attribute__((address_space(3))) void*)l,
                                     16, 0, 0);
}

// ---------------------------------------------------------------------------
// NT-GEMM: C[M,N] = A[M,K] * B[N,K]^T (+ epilogue). 128x128 tile, BK=32,
// 256 threads = 4 waves, each wave a 64x64 quadrant (4x4 frags of 16x16x32).
// T4 counted-vmcnt pipeline, RING-4 / 3-step lookahead: prologue stages
// tiles 0,1,2; per iter: s_waitcnt vmcnt(8) (steady; tail 4,0) -> raw
// s_barrier -> STAGE(ti+3) -> ds_read+MFMA. In-flight loads span ~3 K-steps
// (~900 cyc) — covers HBM latency of the streaming A operand (B is
// L2-resident). Ring-3 (r6) covered only ~600 cyc -> ~400 cyc/step stall.
// Race note: STAGE targets buf (cur+3)%4 = the buffer read in iter ti-1;
// all waves' ds_reads of it completed before their MFMAs, hence before this
// iter's barrier -> safe (same argument as ring-3).
// T5 setprio(1) around the MFMA cluster (stage/compute role diversity).
// T2 LDS swizzle (both-sides, rule #21): rows are 64B = 4x16B slots;
// slot' = slot ^ ((row>>1)&3), applied via pre-swizzled GLOBAL source column
// (LDS dest stays linear for global_load_lds) and matching swizzled ds_read.
// Coalesced bf16 epilogue: C tile staged in LDS at stride 136, then short8
// stores (256B contiguous per 16-lane group). fp32 (EPI 3) stores direct.
// Up to 3 independent GEMMs per dispatch via blockIdx.z (same N,K).
// Bijective XCD swizzle: each XCD owns a contiguous run of row-panels.
// EPI: 0 = none (bf16), 2 = +bias, elu+1 for z<2 / bias for z==2 (bf16),
//      3 = +bias (fp32 out).
// ---------------------------------------------------------------------------
template<int EPI>
__global__ __launch_bounds__(256) void gemm_bt(
    const ushort_t* __restrict__ A0, const ushort_t* __restrict__ A1, const ushort_t* __restrict__ A2,
    const ushort_t* __restrict__ B0, const ushort_t* __restrict__ B1, const ushort_t* __restrict__ B2,
    const float* __restrict__ bias0, const float* __restrict__ bias1, const float* __restrict__ bias2,
    void* __restrict__ C0, void* __restrict__ C1, void* __restrict__ C2,
    int N, int K, int nbx)
{
    // LDS ring-4: A bufs 8KB @ 0/8K/16K/24K; B bufs 8KB @ 32K/40K/48K/56K.
    // Epilogue C tile (128x136 bf16 = 34.8KB) reuses the front.
    __shared__ __align__(16) char lds_raw[65536];

    const int z = blockIdx.z;
    const ushort_t* Ab   = (z == 0) ? A0 : (z == 1) ? A1 : A2;
    const ushort_t* Bm   = (z == 0) ? B0 : (z == 1) ? B1 : B2;
    const float*    bias = (z == 0) ? bias0 : (z == 1) ? bias1 : bias2;
    void*           Cv   = (z == 0) ? C0 : (z == 1) ? C1 : C2;

    // bijective XCD swizzle: XCD k owns wg in [k*cpx, (k+1)*cpx)
    const int cpx = gridDim.x >> 3;
    const int bid = blockIdx.x;
    const int wg  = (bid & 7) * cpx + (bid >> 3);
    const long m0 = (long)(wg / nbx) * 128;
    const long n0 = (long)(wg % nbx) * 128;

    const int t = threadIdx.x;
    const int lane = t & 63;
    const int w = t >> 6;
    const int wr = (w >> 1) * 64;
    const int wc = (w & 1) * 64;
    const int fr = lane & 15;
    const int kq = (lane >> 4) * 8;

    // staging: thread t covers (row = t>>2, slot = t&3); global column is
    // PRE-SWIZZLED so the linear LDS write lands swizzled (rule #21).
    const int srow = t >> 2;          // 0..63
    const int scol = ((t & 3) ^ ((srow >> 1) & 3)) * 8;
    // fragment read: swizzled slot for this thread's (fr, kq) — loop-invariant
    const int kqs = (((kq >> 3) ^ ((fr >> 1) & 3))) * 8;

    auto STAGE = [&](int k0, int buf) {
        char* Ad = lds_raw + buf * 8192;
        char* Bd = lds_raw + 32768 + buf * 8192;
        #pragma unroll
        for (int ro = 0; ro < 2; ++ro) {
            const int row = ro * 64 + srow;
            gl2lds16(Ab + (m0 + row) * (long)K + k0 + scol, Ad + (ro * 256 + w * 64) * 16);
            gl2lds16(Bm + (n0 + row) * (long)K + k0 + scol, Bd + (ro * 256 + w * 64) * 16);
        }
    };

    f32x4 acc[4][4] = {};
    const int nt = K >> 5;            // 16 or 32

    STAGE(0, 0);                      // 4 loads
    STAGE(32, 1);                     // 4 loads
    STAGE(64, 2);                     // 4 loads (12 outstanding)

    int cur = 0;
    for (int ti = 0; ti < nt; ++ti) {
        // wait for STAGE(ti); allow the newest (up to 2) stages to stay in flight
        if (ti + 2 < nt)      { asm volatile("s_waitcnt vmcnt(8)" ::: "memory"); }
        else if (ti + 1 < nt) { asm volatile("s_waitcnt vmcnt(4)" ::: "memory"); }
        else                  { asm volatile("s_waitcnt vmcnt(0)" ::: "memory"); }
        __builtin_amdgcn_sched_barrier(0);
        __builtin_amdgcn_s_barrier();          // publish buf[cur] to all waves
        __builtin_amdgcn_sched_barrier(0);

        const int nb = (cur + 3) & 3;
        if (ti + 3 < nt) STAGE((ti + 3) << 5, nb);   // 3-deep lookahead

        const ushort_t* Asc = (const ushort_t*)(lds_raw + cur * 8192);
        const ushort_t* Bsc = (const ushort_t*)(lds_raw + 32768 + cur * 8192);
        short8 av[4], bv[4];
        #pragma unroll
        for (int mi = 0; mi < 4; ++mi)
            av[mi] = *(const short8*)&Asc[(wr + mi * 16 + fr) * 32 + kqs];
        #pragma unroll
        for (int nf = 0; nf < 4; ++nf)
            bv[nf] = *(const short8*)&Bsc[(wc + nf * 16 + fr) * 32 + kqs];
        __builtin_amdgcn_s_setprio(1);
        #pragma unroll
        for (int mi = 0; mi < 4; ++mi)
            #pragma unroll
            for (int nf = 0; nf < 4; ++nf)
                acc[mi][nf] = __builtin_amdgcn_mfma_f32_16x16x32_bf16(
                    av[mi], bv[nf], acc[mi][nf], 0, 0, 0);
        __builtin_amdgcn_s_setprio(0);

        cur = (cur + 1) & 3;
    }

    const int rj = (lane >> 4) * 4;
    if (EPI == 3) {
        // fp32 direct stores: 16 lanes x 4B = full 64B sectors already.
        float* Cf = (float*)Cv;
        __syncthreads();
        #pragma unroll
        for (int nf = 0; nf < 4; ++nf) {
            const long col = n0 + wc + nf * 16 + fr;
            const float bval = bias[col];
            #pragma unroll
            for (int mi = 0; mi < 4; ++mi)
                #pragma unroll
                for (int j = 0; j < 4; ++j)
                    Cf[(m0 + wr + mi * 16 + rj + j) * (long)N + col] = acc[mi][nf][j] + bval;
        }
    } else {
        // bf16: stage in LDS (stride 136 shorts), coalesced short8 stores.
        ushort_t* Ct = (ushort_t*)lds_raw;     // 128x136 bf16 = 34.8KB
        __syncthreads();                        // K-loop LDS fully retired
        const bool do_elu = (EPI == 2) && (z < 2);
        #pragma unroll
        for (int nf = 0; nf < 4; ++nf) {
            const int coll = wc + nf * 16 + fr;
            const float bval = (EPI >= 2) ? bias[n0 + coll] : 0.0f;
            #pragma unroll
            for (int mi = 0; mi < 4; ++mi) {
                #pragma unroll
                for (int j = 0; j < 4; ++j) {
                    float x = acc[mi][nf][j];
                    if (EPI >= 2) x += bval;
                    if (do_elu) x = (x > 0.0f) ? (x + 1.0f) : __expf(x);
                    Ct[(wr + mi * 16 + rj + j) * 136 + coll] = f2bf(x);
                }
            }
        }
        __syncthreads();
        ushort_t* Cb = (ushort_t*)Cv;
        #pragma unroll
        for (int it = 0; it < 8; ++it) {
            const int idx = it * 256 + t;
            const int r   = idx >> 4;          // 0..127
            const int c8  = (idx & 15) * 8;    // 0..120
            short8 vv = *(const short8*)&Ct[r * 136 + c8];
            *(short8*)(Cb + (m0 + r) * (long)N + n0 + c8) = vv;
        }
    }
}

// ---------------------------------------------------------------------------
// Activation convert: fp32 -> bf16, 8 elems/thread. blockIdx.y picks q/k/v.
// ---------------------------------------------------------------------------
__global__ __launch_bounds__(256) void cvt_act(const float* __restrict__ q,
                                               const float* __restrict__ k,
                                               const float* __restrict__ v,
                                               ushort_t* __restrict__ qo,
                                               ushort_t* __restrict__ ko,
                                               ushort_t* __restrict__ vo)
{
    const int zz = blockIdx.y;
    const float* src = (zz == 0) ? q : (zz == 1) ? k : v;
    ushort_t*    dst = (zz == 0) ? qo : (zz == 1) ? ko : vo;
    const long i = ((long)blockIdx.x * 256 + threadIdx.x) * 8;
    f32x4 f0 = *(const f32x4*)(src + i);
    f32x4 f1 = *(const f32x4*)(src + i + 4);
    short8 h;
    h[0] = (short)f2bf(f0[0]); h[1] = (short)f2bf(f0[1]);
    h[2] = (short)f2bf(f0[2]); h[3] = (short)f2bf(f0[3]);
    h[4] = (short)f2bf(f1[0]); h[5] = (short)f2bf(f1[1]);
    h[6] = (short)f2bf(f1[2]); h[7] = (short)f2bf(f1[3]);
    *(short8*)(dst + i) = h;
}

// ---------------------------------------------------------------------------
// All 7 weight conversions in one dispatch. blockIdx.y selects the weight.
// ---------------------------------------------------------------------------
__global__ __launch_bounds__(256) void cvt_weights(
    const float* __restrict__ s0, const float* __restrict__ s1,
    const float* __restrict__ s2, const float* __restrict__ s3,
    const float* __restrict__ s4, const float* __restrict__ s5,
    const float* __restrict__ s6,
    ushort_t* __restrict__ d0, ushort_t* __restrict__ d1,
    ushort_t* __restrict__ d2, ushort_t* __restrict__ d3,
    ushort_t* __restrict__ d4, ushort_t* __restrict__ d5,
    ushort_t* __restrict__ d6)
{
    const int y = blockIdx.y;
    const float* src; ushort_t* dst; int n;
    switch (y) {
        case 0: src = s0; dst = d0; n = RANK * EMBED; break;
        case 1: src = s1; dst = d1; n = RANK * EMBED; break;
        case 2: src = s2; dst = d2; n = RANK * EMBED; break;
        case 3: src = s3; dst = d3; n = RANK * EMBED; break;
        case 4: src = s4; dst = d4; n = RANK * EMBED; break;
        case 5: src = s5; dst = d5; n = RANK * EMBED; break;
        default: src = s6; dst = d6; n = EMBED * EMBED; break;
    }
    const int i = (blockIdx.x * 256 + threadIdx.x) * 4;
    if (i < n) {
        f32x4 f = *(const f32x4*)(src + i);
        typedef __attribute__((ext_vector_type(4))) short short4v;
        short4v h;
        h[0] = (short)f2bf(f[0]); h[1] = (short)f2bf(f[1]);
        h[2] = (short)f2bf(f[2]); h[3] = (short)f2bf(f[3]);
        *(short4v*)(dst + i) = h;
    }
}

// ---------------------------------------------------------------------------
// Per-head partial stats over a 256-row n-chunk:
//   kvp[chunk][bh][e][d] = sum_n V[n,e]*K[n,d];  ksump[chunk][bh][d] = sum_n K[n,d]
// Grid: (64 bh, NCHUNK). 256 threads; thread owns 4 e x 4 d register tile.
// ---------------------------------------------------------------------------
__global__ __launch_bounds__(256) void kv_stats(const ushort_t* __restrict__ Kp,
                                                const ushort_t* __restrict__ Vp,
                                                float* __restrict__ kvp,
                                                float* __restrict__ ksump)
{
    __shared__ __align__(16) ushort_t Ks[64 * 64];
    __shared__ __align__(16) ushort_t Vs[64 * 64];
    const int t = threadIdx.x;
    const int w = t >> 6;
    const int bh = blockIdx.x;
    const int chunk = blockIdx.y;
    const int b = bh >> 4, h = bh & 15;
    const int d0 = (t & 15) * 4;
    const int e0 = (t >> 4) * 4;
    float acc[4][4] = {};
    float sks[4] = {};
    const long hbase = ((long)b * SS) * EMBED + h * DHD;

    for (int sub = 0; sub < 4; ++sub) {
        const int n00 = chunk * 256 + sub * 64;
        #pragma unroll
        for (int ro = 0; ro < 2; ++ro) {
            const int idx = ro * 256 + t;
            const int r = idx >> 3, c16 = idx & 7;
            const long g = hbase + (long)(n00 + r) * EMBED + c16 * 8;
            gl2lds16(Kp + g, (char*)Ks + (ro * 256 + w * 64) * 16);
            gl2lds16(Vp + g, (char*)Vs + (ro * 256 + w * 64) * 16);
        }
        __syncthreads();
        #pragma unroll 8
        for (int n = 0; n < 64; ++n) {
            const uint_t* kr = (const uint_t*)(Ks + n * 64 + d0);
            const uint_t* vr = (const uint_t*)(Vs + n * 64 + e0);
            const uint_t k01 = kr[0], k23 = kr[1];
            const uint_t v01 = vr[0], v23 = vr[1];
            float kd[4], ve[4];
            {
                union { uint_t i; float f; } a, bq, c, dq;
                a.i = k01 << 16; bq.i = k01 & 0xffff0000u;
                c.i = k23 << 16; dq.i = k23 & 0xffff0000u;
                kd[0] = a.f; kd[1] = bq.f; kd[2] = c.f; kd[3] = dq.f;
            }
            {
                union { uint_t i; float f; } a, bq, c, dq;
                a.i = v01 << 16; bq.i = v01 & 0xffff0000u;
                c.i = v23 << 16; dq.i = v23 & 0xffff0000u;
                ve[0] = a.f; ve[1] = bq.f; ve[2] = c.f; ve[3] = dq.f;
            }
            #pragma unroll
            for (int e = 0; e < 4; ++e)
                #pragma unroll
                for (int d = 0; d < 4; ++d)
                    acc[e][d] += ve[e] * kd[d];
            if (e0 == 0) {
                #pragma unroll
                for (int d = 0; d < 4; ++d) sks[d] += kd[d];
            }
        }
        __syncthreads();
    }

    float* dst = kvp + ((long)chunk * 64 + bh) * 4096;
    #pragma unroll
    for (int e = 0; e < 4; ++e) {
        f32x4 vv; vv[0] = acc[e][0]; vv[1] = acc[e][1]; vv[2] = acc[e][2]; vv[3] = acc[e][3];
        *(f32x4*)(dst + (e0 + e) * 64 + d0) = vv;
    }
    if (e0 == 0) {
        float* sd = ksump + ((long)chunk * 64 + bh) * 64 + d0;
        #pragma unroll
        for (int d = 0; d < 4; ++d) sd[d] = sks[d];
    }
}

// ---------------------------------------------------------------------------
// Reduce NCHUNK partials -> kvb (bf16) and ksumf (f32). Grid: 64 blocks.
// ---------------------------------------------------------------------------
__global__ __launch_bounds__(256) void kv_reduce(const float* __restrict__ kvp,
                                                 const float* __restrict__ ksump,
                                                 ushort_t* __restrict__ kvb,
                                                 float* __restrict__ ksumf)
{
    const int bh = blockIdx.x;
    const int t = threadIdx.x;
    const long base = (long)bh * 4096 + t * 16;
    f32x4 s[4] = {};
    #pragma unroll 4
    for (int c = 0; c < NCHUNK; ++c) {
        const float* src = kvp + (long)c * 64 * 4096 + base;
        #pragma unroll
        for (int j = 0; j < 4; ++j) s[j] += *(const f32x4*)(src + j * 4);
    }
    short8 o0, o1;
    #pragma unroll
    for (int j = 0; j < 4; ++j) {
        o0[j]     = (short)f2bf(s[0][j]); o0[4 + j] = (short)f2bf(s[1][j]);
        o1[j]     = (short)f2bf(s[2][j]); o1[4 + j] = (short)f2bf(s[3][j]);
    }
    *(short8*)(kvb + base)     = o0;
    *(short8*)(kvb + base + 8) = o1;

    if (t < 64) {
        float ss = 0.f;
        #pragma unroll
        for (int c = 0; c < NCHUNK; ++c) ss += ksump[(long)c * 64 * 64 + bh * 64 + t];
        ksumf[bh * 64 + t] = ss;
    }
}

// ---------------------------------------------------------------------------
// num = phi(q) @ kvT^T ; denom = phi(q) . ksum ; O = num/(denom+1e-6), bf16.
// Grid: (64 bh, 32 chunks of 128 rows). 4 waves, wave w owns rows w*32..+32.
// ---------------------------------------------------------------------------
__global__ __launch_bounds__(256) void attn_out(const ushort_t* __restrict__ Qp,
                                                const ushort_t* __restrict__ kvb,
                                                const float* __restrict__ ksum,
                                                ushort_t* __restrict__ Op)
{
    __shared__ __align__(16) ushort_t Qs[128 * 64];
    __shared__ __align__(16) ushort_t KVs[64 * 64];
    __shared__ float kss[64];
    __shared__ float dnm[128];
    const int t = threadIdx.x;
    const int w = t >> 6, lane = t & 63;
    const int bh = blockIdx.x, mc = blockIdx.y;
    const int b = bh >> 4, h = bh & 15;
    const long base = ((long)b * SS + mc * 128) * EMBED + h * DHD;

    #pragma unroll
    for (int ro = 0; ro < 4; ++ro) {
        const int idx = ro * 256 + t;
        const int r = idx >> 3, c16 = idx & 7;
        gl2lds16(Qp + base + (long)r * EMBED + c16 * 8,
                 (char*)Qs + (ro * 256 + w * 64) * 16);
    }
    #pragma unroll
    for (int ro = 0; ro < 2; ++ro) {
        const int idx = ro * 256 + t;
        gl2lds16(kvb + (long)bh * 4096 + idx * 8,
                 (char*)KVs + (ro * 256 + w * 64) * 16);
    }
    if (t < 64) kss[t] = ksum[bh * 64 + t];
    __syncthreads();

    if (t < 128) {   // denominator per row
        float s = 0.f;
        const uint_t* qr = (const uint_t*)(Qs + t * 64);
        #pragma unroll
        for (int jj = 0; jj < 32; ++jj) {
            const uint_t u = qr[jj];
            union { uint_t i; float f; } lo, hi;
            lo.i = u << 16; hi.i = u & 0xffff0000u;
            s += lo.f * kss[2 * jj] + hi.f * kss[2 * jj + 1];
        }
        dnm[t] = s;
    }

    const int fr = lane & 15, kq = (lane >> 4) * 8;
    f32x4 acc[2][4] = {};
    #pragma unroll
    for (int ks = 0; ks < 2; ++ks) {
        short8 av[2], bv[4];
        #pragma unroll
        for (int mi = 0; mi < 2; ++mi)
            av[mi] = *(const short8*)&Qs[(w * 32 + mi * 16 + fr) * 64 + ks * 32 + kq];
        #pragma unroll
        for (int nf = 0; nf < 4; ++nf)
            bv[nf] = *(const short8*)&KVs[(nf * 16 + fr) * 64 + ks * 32 + kq];
        #pragma unroll
        for (int mi = 0; mi < 2; ++mi)
            #pragma unroll
            for (int nf = 0; nf < 4; ++nf)
                acc[mi][nf] = __builtin_amdgcn_mfma_f32_16x16x32_bf16(
                    av[mi], bv[nf], acc[mi][nf], 0, 0, 0);
    }
    __syncthreads();

    const int rj = (lane >> 4) * 4;
    #pragma unroll
    for (int mi = 0; mi < 2; ++mi) {
        #pragma unroll
        for (int nf = 0; nf < 4; ++nf) {
            #pragma unroll
            for (int j = 0; j < 4; ++j) {
                const int r = w * 32 + mi * 16 + rj + j;
                const int c = nf * 16 + fr;
                const float x = acc[mi][nf][j] / (dnm[r] + 1e-6f);
                Op[base + (long)r * EMBED + c] = f2bf(x);
            }
        }
    }
}

// ---------------------------------------------------------------------------
extern "C" void kernel_launch(void* const* d_in, const int* in_sizes, int n_in,
                              void* d_out, int out_size, void* d_ws, size_t ws_size,
                              hipStream_t stream)
{
    (void)in_sizes; (void)n_in; (void)out_size; (void)ws_size;
    const float* query = (const float*)d_in[0];
    const float* key_  = (const float*)d_in[1];
    const float* value = (const float*)d_in[2];
    const float* q_dw  = (const float*)d_in[3];
    const float* q_uw  = (const float*)d_in[4];
    const float* q_ub  = (const float*)d_in[5];
    const float* k_dw  = (const float*)d_in[6];
    const float* k_uw  = (const float*)d_in[7];
    const float* k_ub  = (const float*)d_in[8];
    const float* v_dw  = (const float*)d_in[9];
    const float* v_uw  = (const float*)d_in[10];
    const float* v_ub  = (const float*)d_in[11];
    const float* o_w   = (const float*)d_in[12];
    const float* o_b   = (const float*)d_in[13];

    char* ws = (char*)d_ws;
    size_t off = 0;
    auto alloc = [&](size_t bytes) -> void* {
        void* p = ws + off;
        off += (bytes + 255) & ~(size_t)255;
        return p;
    };
    const size_t WSMALL = (size_t)RANK * EMBED;   // 524288
    ushort_t* bw_qd = (ushort_t*)alloc(WSMALL * 2);
    ushort_t* bw_qu = (ushort_t*)alloc(WSMALL * 2);
    ushort_t* bw_kd = (ushort_t*)alloc(WSMALL * 2);
    ushort_t* bw_ku = (ushort_t*)alloc(WSMALL * 2);
    ushort_t* bw_vd = (ushort_t*)alloc(WSMALL * 2);
    ushort_t* bw_vu = (ushort_t*)alloc(WSMALL * 2);
    ushort_t* bw_o  = (ushort_t*)alloc((size_t)EMBED * EMBED * 2);
    ushort_t* Qb    = (ushort_t*)alloc((size_t)MM * EMBED * 2);   // 33.55 MB
    ushort_t* Kb    = (ushort_t*)alloc((size_t)MM * EMBED * 2);
    ushort_t* Vb    = (ushort_t*)alloc((size_t)MM * EMBED * 2);
    ushort_t* Y1q   = (ushort_t*)alloc((size_t)MM * RANK * 2);    // 16.78 MB
    ushort_t* Y1k   = (ushort_t*)alloc((size_t)MM * RANK * 2);
    ushort_t* Y1v   = (ushort_t*)alloc((size_t)MM * RANK * 2);
    float*    ksump = (float*)alloc((size_t)NCHUNK * 64 * 64 * 4);
    float*    ksumf = (float*)alloc((size_t)64 * 64 * 4);
    ushort_t* kvb   = (ushort_t*)alloc((size_t)64 * 64 * 64 * 2);

    // Aliases (lifetime-disjoint):
    //  PQ/PK/PV reuse Qb/Kb/Vb (dead after down-proj).
    //  kvp (NCHUNK*64*4096*4 = 16,777,216 B) reuses Y1q (dead after up-proj).
    //  O (33.55 MB) reuses Y1k+Y1v (contiguous 2x16,777,216 B, 256-aligned).
    ushort_t* PQ = Qb;
    ushort_t* PK = Kb;
    ushort_t* PV = Vb;
    float*    kvp = (float*)Y1q;
    ushort_t* O   = Y1k;

    const dim3 blk(256);

    // converts: QKV activations (8 elems/thread) + 7 weights
    cvt_act<<<dim3((size_t)MM * EMBED / 2048, 3), blk, 0, stream>>>(
        query, key_, value, Qb, Kb, Vb);
    cvt_weights<<<dim3(EMBED * EMBED / 1024, 7), blk, 0, stream>>>(
        q_dw, q_uw, k_dw, k_uw, v_dw, v_uw, o_w,
        bw_qd, bw_qu, bw_kd, bw_ku, bw_vd, bw_vu, bw_o);

    // 3 down-projections in one dispatch (pure bf16)
    gemm_bt<0><<<dim3(MM / 128 * (RANK / 128), 1, 3), blk, 0, stream>>>(
        Qb, Kb, Vb,
        bw_qd, bw_kd, bw_vd,
        nullptr, nullptr, nullptr,
        Y1q, Y1k, Y1v,
        RANK, EMBED, RANK / 128);

    // 3 up-projections: z=0 q (elu+1), z=1 k (elu+1), z=2 v (bias only)
    gemm_bt<2><<<dim3(MM / 128 * (EMBED / 128), 1, 3), blk, 0, stream>>>(
        Y1q, Y1k, Y1v,
        bw_qu, bw_ku, bw_vu,
        q_ub, k_ub, v_ub,
        PQ, PK, PV,
        EMBED, RANK, EMBED / 128);

    kv_stats<<<dim3(64, NCHUNK), blk, 0, stream>>>(PK, PV, kvp, ksump);
    kv_reduce<<<dim3(64), blk, 0, stream>>>(kvp, ksump, kvb, ksumf);
    attn_out<<<dim3(64, 32), blk, 0, stream>>>(PQ, kvb, ksumf, O);

    // output projection (fp32 out)
    gemm_bt<3><<<dim3(MM / 128 * (EMBED / 128), 1, 1), blk, 0, stream>>>(
        O, nullptr, nullptr,
        bw_o, nullptr, nullptr,
        o_b, nullptr, nullptr,
        d_out, nullptr, nullptr,
        EMBED, EMBED, EMBED / 128);
}

// Round 9
// 318.482 us; speedup vs baseline: 1.0673x; 1.0012x over previous
//
#include <hip/hip_runtime.h>
#include <hip/hip_bf16.h>

typedef unsigned short ushort_t;
typedef unsigned int uint_t;
typedef __attribute__((ext_vector_type(8))) short short8;
typedef __attribute__((ext_vector_type(4))) float f32x4;

#define EMBED 1024
#define RANK  512
#define BB    4
#define SS    4096
#define HH    16
#define DHD   64
#define MM    (BB*SS)   // 16384 rows
#define NCHUNK 16       // kv_stats n-parallelism (256 rows per chunk)

__device__ __forceinline__ float bf2f(ushort_t u) {
    union { uint_t i; float f; } v; v.i = ((uint_t)u) << 16; return v.f;
}
__device__ __forceinline__ ushort_t f2bf(float f) {
    union { float f; uint_t i; } v; v.f = f;
    uint_t r = v.i + 0x7FFFu + ((v.i >> 16) & 1u);   // RNE
    return (ushort_t)(r >> 16);
}
// async global->LDS, 16B per lane; LDS dest must be wave-uniform base (+lane*16 in HW)
__device__ __forceinline__ void gl2lds16(const void* g, void* l) {
    __builtin_amdgcn_global_load_lds((const __attribute__((address_space(1))) void*)g,
                                     (__attribute__((address_space(3))) void*)l,
                                     16, 0, 0);
}

// ---------------------------------------------------------------------------
// NT-GEMM (bf16 A): C[M,N] = A[M,K]*B[N,K]^T (+epilogue). 128x128 tile, BK=32,
// 4 waves, each a 64x64 quadrant. RING-3 counted-vmcnt pipeline (r6 config,
// the measured local optimum: 48KB LDS -> 3 blocks/CU): prologue stages
// tiles 0,1; per iter vmcnt(4) (never 0 until tail) -> raw s_barrier ->
// STAGE(ti+2) -> ds_read+MFMA. T2 swizzle via pre-swizzled global source col
// + matching swizzled ds_read (rule #21). Coalesced bf16 epilogue via LDS.
// EPI: 2 = +bias, elu+1 for z<2 / bias for z==2 (bf16); 3 = +bias (fp32).
// ---------------------------------------------------------------------------
template<int EPI>
__global__ __launch_bounds__(256) void gemm_bt(
    const ushort_t* __restrict__ A0, const ushort_t* __restrict__ A1, const ushort_t* __restrict__ A2,
    const ushort_t* __restrict__ B0, const ushort_t* __restrict__ B1, const ushort_t* __restrict__ B2,
    const float* __restrict__ bias0, const float* __restrict__ bias1, const float* __restrict__ bias2,
    void* __restrict__ C0, void* __restrict__ C1, void* __restrict__ C2,
    int N, int K, int nbx)
{
    // LDS ring-3: A bufs 8KB @ 0/8K/16K; B bufs @ 24K/32K/40K.
    // Epilogue C tile (128x136 bf16 = 34.8KB) reuses the front.
    __shared__ __align__(16) char lds_raw[49152];

    const int z = blockIdx.z;
    const ushort_t* Ab   = (z == 0) ? A0 : (z == 1) ? A1 : A2;
    const ushort_t* Bm   = (z == 0) ? B0 : (z == 1) ? B1 : B2;
    const float*    bias = (z == 0) ? bias0 : (z == 1) ? bias1 : bias2;
    void*           Cv   = (z == 0) ? C0 : (z == 1) ? C1 : C2;

    const int cpx = gridDim.x >> 3;
    const int bid = blockIdx.x;
    const int wg  = (bid & 7) * cpx + (bid >> 3);
    const long m0 = (long)(wg / nbx) * 128;
    const long n0 = (long)(wg % nbx) * 128;

    const int t = threadIdx.x;
    const int lane = t & 63;
    const int w = t >> 6;
    const int wr = (w >> 1) * 64;
    const int wc = (w & 1) * 64;
    const int fr = lane & 15;
    const int kq = (lane >> 4) * 8;

    const int srow = t >> 2;          // 0..63
    const int scol = ((t & 3) ^ ((srow >> 1) & 3)) * 8;
    const int kqs = (((kq >> 3) ^ ((fr >> 1) & 3))) * 8;

    auto STAGE = [&](int k0, int buf) {
        char* Ad = lds_raw + buf * 8192;
        char* Bd = lds_raw + 24576 + buf * 8192;
        #pragma unroll
        for (int ro = 0; ro < 2; ++ro) {
            const int row = ro * 64 + srow;
            gl2lds16(Ab + (m0 + row) * (long)K + k0 + scol, Ad + (ro * 256 + w * 64) * 16);
            gl2lds16(Bm + (n0 + row) * (long)K + k0 + scol, Bd + (ro * 256 + w * 64) * 16);
        }
    };

    f32x4 acc[4][4] = {};
    const int nt = K >> 5;

    STAGE(0, 0);
    STAGE(32, 1);

    int cur = 0;
    for (int ti = 0; ti < nt; ++ti) {
        if (ti + 1 < nt) { asm volatile("s_waitcnt vmcnt(4)" ::: "memory"); }
        else             { asm volatile("s_waitcnt vmcnt(0)" ::: "memory"); }
        __builtin_amdgcn_sched_barrier(0);
        __builtin_amdgcn_s_barrier();          // publish buf[cur]
        __builtin_amdgcn_sched_barrier(0);

        int nb = cur + 2; if (nb >= 3) nb -= 3;
        if (ti + 2 < nt) STAGE((ti + 2) << 5, nb);

        const ushort_t* Asc = (const ushort_t*)(lds_raw + cur * 8192);
        const ushort_t* Bsc = (const ushort_t*)(lds_raw + 24576 + cur * 8192);
        short8 av[4], bv[4];
        #pragma unroll
        for (int mi = 0; mi < 4; ++mi)
            av[mi] = *(const short8*)&Asc[(wr + mi * 16 + fr) * 32 + kqs];
        #pragma unroll
        for (int nf = 0; nf < 4; ++nf)
            bv[nf] = *(const short8*)&Bsc[(wc + nf * 16 + fr) * 32 + kqs];
        #pragma unroll
        for (int mi = 0; mi < 4; ++mi)
            #pragma unroll
            for (int nf = 0; nf < 4; ++nf)
                acc[mi][nf] = __builtin_amdgcn_mfma_f32_16x16x32_bf16(
                    av[mi], bv[nf], acc[mi][nf], 0, 0, 0);

        ++cur; if (cur == 3) cur = 0;
    }

    const int rj = (lane >> 4) * 4;
    if (EPI == 3) {
        float* Cf = (float*)Cv;
        __syncthreads();
        #pragma unroll
        for (int nf = 0; nf < 4; ++nf) {
            const long col = n0 + wc + nf * 16 + fr;
            const float bval = bias[col];
            #pragma unroll
            for (int mi = 0; mi < 4; ++mi)
                #pragma unroll
                for (int j = 0; j < 4; ++j)
                    Cf[(m0 + wr + mi * 16 + rj + j) * (long)N + col] = acc[mi][nf][j] + bval;
        }
    } else {
        ushort_t* Ct = (ushort_t*)lds_raw;     // 128x136 bf16 = 34.8KB
        __syncthreads();
        const bool do_elu = (EPI == 2) && (z < 2);
        #pragma unroll
        for (int nf = 0; nf < 4; ++nf) {
            const int coll = wc + nf * 16 + fr;
            const float bval = (EPI >= 2) ? bias[n0 + coll] : 0.0f;
            #pragma unroll
            for (int mi = 0; mi < 4; ++mi) {
                #pragma unroll
                for (int j = 0; j < 4; ++j) {
                    float x = acc[mi][nf][j];
                    if (EPI >= 2) x += bval;
                    if (do_elu) x = (x > 0.0f) ? (x + 1.0f) : __expf(x);
                    Ct[(wr + mi * 16 + rj + j) * 136 + coll] = f2bf(x);
                }
            }
        }
        __syncthreads();
        ushort_t* Cb = (ushort_t*)Cv;
        #pragma unroll
        for (int it = 0; it < 8; ++it) {
            const int idx = it * 256 + t;
            const int r   = idx >> 4;
            const int c8  = (idx & 15) * 8;
            short8 vv = *(const short8*)&Ct[r * 136 + c8];
            *(short8*)(Cb + (m0 + r) * (long)N + n0 + c8) = vv;
        }
    }
}

// ---------------------------------------------------------------------------
// Down-proj NT-GEMM with FUSED fp32->bf16 A conversion (replaces cvt_act).
// 128x128 tile, BK=32, 4 waves. 2-phase double-buffer with __syncthreads
// (trivially race-free; compiler tracks the SSA A-reg loads). T14-lite:
// next tile's A fp32 loads (4x dwordx4/thread) + B global_load_lds issued
// at iter top; MFMAs run while they land; convert+ds_write A after MFMA;
// __syncthreads publishes. A-swizzle applied on the ds_write address
// (per-lane scatter - both-sides consistent with the kqs read); B-swizzle
// via pre-swizzled global source col as usual. LDS 36KB -> 4 blocks/CU.
// EPI 0: no bias, bf16 out (coalesced LDS-staged epilogue).
// ---------------------------------------------------------------------------
__global__ __launch_bounds__(256) void gemm_dn(
    const float* __restrict__ A0, const float* __restrict__ A1, const float* __restrict__ A2,
    const ushort_t* __restrict__ B0, const ushort_t* __restrict__ B1, const ushort_t* __restrict__ B2,
    void* __restrict__ C0, void* __restrict__ C1, void* __restrict__ C2,
    int N, int K, int nbx)
{
    // A bufs 8KB @ 0/8K; B bufs 8KB @ 16K/24K; epilogue Ct (34.8KB) overlays.
    __shared__ __align__(16) char lds_raw[36864];

    const int z = blockIdx.z;
    const float*    Af = (z == 0) ? A0 : (z == 1) ? A1 : A2;
    const ushort_t* Bm = (z == 0) ? B0 : (z == 1) ? B1 : B2;
    void*           Cv = (z == 0) ? C0 : (z == 1) ? C1 : C2;

    const int cpx = gridDim.x >> 3;
    const int bid = blockIdx.x;
    const int wg  = (bid & 7) * cpx + (bid >> 3);
    const long m0 = (long)(wg / nbx) * 128;
    const long n0 = (long)(wg % nbx) * 128;

    const int t = threadIdx.x;
    const int lane = t & 63;
    const int w = t >> 6;
    const int wr = (w >> 1) * 64;
    const int wc = (w & 1) * 64;
    const int fr = lane & 15;
    const int kq = (lane >> 4) * 8;

    // B staging (gl2lds): thread t covers (row=t>>2 of 64, slot=t&3), source
    // column pre-swizzled.
    const int srow = t >> 2;
    const int scol = ((t & 3) ^ ((srow >> 1) & 3)) * 8;
    // fragment-read swizzled slot
    const int kqs = (((kq >> 3) ^ ((fr >> 1) & 3))) * 8;

    // A reg-staging: thread t covers row = t>>1 (0..127), fp32 cols
    // acolh..acolh+15; writes bf16 slots {2*(t&1), 2*(t&1)+1} XOR-swizzled.
    const int arow  = t >> 1;
    const int acolh = (t & 1) * 16;
    const int asw   = (arow >> 1) & 3;
    const int as0   = (2 * (t & 1)) ^ asw;
    const int as1   = (2 * (t & 1) + 1) ^ asw;

    auto LOADA = [&](int k0, f32x4* ra) {
        const float* src = Af + (m0 + arow) * (long)K + k0 + acolh;
        #pragma unroll
        for (int j = 0; j < 4; ++j) ra[j] = *(const f32x4*)(src + 4 * j);
    };
    auto LOADB = [&](int k0, int buf) {
        char* Bd = lds_raw + 16384 + buf * 8192;
        #pragma unroll
        for (int ro = 0; ro < 2; ++ro) {
            const int row = ro * 64 + srow;
            gl2lds16(Bm + (n0 + row) * (long)K + k0 + scol, Bd + (ro * 256 + w * 64) * 16);
        }
    };
    auto WRITEA = [&](const f32x4* ra, int buf) {
        ushort_t* Ad = (ushort_t*)(lds_raw + buf * 8192);
        short8 h0, h1;
        #pragma unroll
        for (int j = 0; j < 4; ++j) {
            h0[2 * j]     = (short)f2bf(ra[j >> 1][(j & 1) * 2]);
            h0[2 * j + 1] = (short)f2bf(ra[j >> 1][(j & 1) * 2 + 1]);
            h1[2 * j]     = (short)f2bf(ra[2 + (j >> 1)][(j & 1) * 2]);
            h1[2 * j + 1] = (short)f2bf(ra[2 + (j >> 1)][(j & 1) * 2 + 1]);
        }
        *(short8*)&Ad[arow * 32 + as0 * 8] = h0;
        *(short8*)&Ad[arow * 32 + as1 * 8] = h1;
    };

    f32x4 acc[4][4] = {};
    const int nt = K >> 5;            // 32

    f32x4 ra[4];
    LOADA(0, ra);
    LOADB(0, 0);
    WRITEA(ra, 0);                     // compiler waits the reg loads
    __syncthreads();                   // drains B(0) + publishes A(0)

    int cur = 0;
    for (int ti = 0; ti < nt; ++ti) {
        if (ti + 1 < nt) {
            LOADA((ti + 1) << 5, ra);  // issue early: lands under MFMA
            LOADB((ti + 1) << 5, cur ^ 1);
        }

        const ushort_t* Asc = (const ushort_t*)(lds_raw + cur * 8192);
        const ushort_t* Bsc = (const ushort_t*)(lds_raw + 16384 + cur * 8192);
        short8 av[4], bv[4];
        #pragma unroll
        for (int mi = 0; mi < 4; ++mi)
            av[mi] = *(const short8*)&Asc[(wr + mi * 16 + fr) * 32 + kqs];
        #pragma unroll
        for (int nf = 0; nf < 4; ++nf)
            bv[nf] = *(const short8*)&Bsc[(wc + nf * 16 + fr) * 32 + kqs];
        #pragma unroll
        for (int mi = 0; mi < 4; ++mi)
            #pragma unroll
            for (int nf = 0; nf < 4; ++nf)
                acc[mi][nf] = __builtin_amdgcn_mfma_f32_16x16x32_bf16(
                    av[mi], bv[nf], acc[mi][nf], 0, 0, 0);

        if (ti + 1 < nt) WRITEA(ra, cur ^ 1);   // convert late, write other buf
        __syncthreads();                         // publish buf[cur^1]
        cur ^= 1;
    }

    // bf16 coalesced epilogue via LDS (no bias)
    ushort_t* Ct = (ushort_t*)lds_raw;           // 128x136 = 34.8KB
    const int rj = (lane >> 4) * 4;
    #pragma unroll
    for (int nf = 0; nf < 4; ++nf) {
        const int coll = wc + nf * 16 + fr;
        #pragma unroll
        for (int mi = 0; mi < 4; ++mi)
            #pragma unroll
            for (int j = 0; j < 4; ++j)
                Ct[(wr + mi * 16 + rj + j) * 136 + coll] = f2bf(acc[mi][nf][j]);
    }
    __syncthreads();
    ushort_t* Cb = (ushort_t*)Cv;
    #pragma unroll
    for (int it = 0; it < 8; ++it) {
        const int idx = it * 256 + t;
        const int r   = idx >> 4;
        const int c8  = (idx & 15) * 8;
        short8 vv = *(const short8*)&Ct[r * 136 + c8];
        *(short8*)(Cb + (m0 + r) * (long)N + n0 + c8) = vv;
    }
}

// ---------------------------------------------------------------------------
// All 7 weight conversions in one dispatch. blockIdx.y selects the weight.
// ---------------------------------------------------------------------------
__global__ __launch_bounds__(256) void cvt_weights(
    const float* __restrict__ s0, const float* __restrict__ s1,
    const float* __restrict__ s2, const float* __restrict__ s3,
    const float* __restrict__ s4, const float* __restrict__ s5,
    const float* __restrict__ s6,
    ushort_t* __restrict__ d0, ushort_t* __restrict__ d1,
    ushort_t* __restrict__ d2, ushort_t* __restrict__ d3,
    ushort_t* __restrict__ d4, ushort_t* __restrict__ d5,
    ushort_t* __restrict__ d6)
{
    const int y = blockIdx.y;
    const float* src; ushort_t* dst; int n;
    switch (y) {
        case 0: src = s0; dst = d0; n = RANK * EMBED; break;
        case 1: src = s1; dst = d1; n = RANK * EMBED; break;
        case 2: src = s2; dst = d2; n = RANK * EMBED; break;
        case 3: src = s3; dst = d3; n = RANK * EMBED; break;
        case 4: src = s4; dst = d4; n = RANK * EMBED; break;
        case 5: src = s5; dst = d5; n = RANK * EMBED; break;
        default: src = s6; dst = d6; n = EMBED * EMBED; break;
    }
    const int i = (blockIdx.x * 256 + threadIdx.x) * 4;
    if (i < n) {
        f32x4 f = *(const f32x4*)(src + i);
        typedef __attribute__((ext_vector_type(4))) short short4v;
        short4v h;
        h[0] = (short)f2bf(f[0]); h[1] = (short)f2bf(f[1]);
        h[2] = (short)f2bf(f[2]); h[3] = (short)f2bf(f[3]);
        *(short4v*)(dst + i) = h;
    }
}

// ---------------------------------------------------------------------------
// Per-head partial stats over a 256-row n-chunk:
//   kvp[chunk][bh][e][d] = sum_n V[n,e]*K[n,d];  ksump[chunk][bh][d] = sum_n K[n,d]
// ---------------------------------------------------------------------------
__global__ __launch_bounds__(256) void kv_stats(const ushort_t* __restrict__ Kp,
                                                const ushort_t* __restrict__ Vp,
                                                float* __restrict__ kvp,
                                                float* __restrict__ ksump)
{
    __shared__ __align__(16) ushort_t Ks[64 * 64];
    __shared__ __align__(16) ushort_t Vs[64 * 64];
    const int t = threadIdx.x;
    const int w = t >> 6;
    const int bh = blockIdx.x;
    const int chunk = blockIdx.y;
    const int b = bh >> 4, h = bh & 15;
    const int d0 = (t & 15) * 4;
    const int e0 = (t >> 4) * 4;
    float acc[4][4] = {};
    float sks[4] = {};
    const long hbase = ((long)b * SS) * EMBED + h * DHD;

    for (int sub = 0; sub < 4; ++sub) {
        const int n00 = chunk * 256 + sub * 64;
        #pragma unroll
        for (int ro = 0; ro < 2; ++ro) {
            const int idx = ro * 256 + t;
            const int r = idx >> 3, c16 = idx & 7;
            const long g = hbase + (long)(n00 + r) * EMBED + c16 * 8;
            gl2lds16(Kp + g, (char*)Ks + (ro * 256 + w * 64) * 16);
            gl2lds16(Vp + g, (char*)Vs + (ro * 256 + w * 64) * 16);
        }
        __syncthreads();
        #pragma unroll 8
        for (int n = 0; n < 64; ++n) {
            const uint_t* kr = (const uint_t*)(Ks + n * 64 + d0);
            const uint_t* vr = (const uint_t*)(Vs + n * 64 + e0);
            const uint_t k01 = kr[0], k23 = kr[1];
            const uint_t v01 = vr[0], v23 = vr[1];
            float kd[4], ve[4];
            {
                union { uint_t i; float f; } a, bq, c, dq;
                a.i = k01 << 16; bq.i = k01 & 0xffff0000u;
                c.i = k23 << 16; dq.i = k23 & 0xffff0000u;
                kd[0] = a.f; kd[1] = bq.f; kd[2] = c.f; kd[3] = dq.f;
            }
            {
                union { uint_t i; float f; } a, bq, c, dq;
                a.i = v01 << 16; bq.i = v01 & 0xffff0000u;
                c.i = v23 << 16; dq.i = v23 & 0xffff0000u;
                ve[0] = a.f; ve[1] = bq.f; ve[2] = c.f; ve[3] = dq.f;
            }
            #pragma unroll
            for (int e = 0; e < 4; ++e)
                #pragma unroll
                for (int d = 0; d < 4; ++d)
                    acc[e][d] += ve[e] * kd[d];
            if (e0 == 0) {
                #pragma unroll
                for (int d = 0; d < 4; ++d) sks[d] += kd[d];
            }
        }
        __syncthreads();
    }

    float* dst = kvp + ((long)chunk * 64 + bh) * 4096;
    #pragma unroll
    for (int e = 0; e < 4; ++e) {
        f32x4 vv; vv[0] = acc[e][0]; vv[1] = acc[e][1]; vv[2] = acc[e][2]; vv[3] = acc[e][3];
        *(f32x4*)(dst + (e0 + e) * 64 + d0) = vv;
    }
    if (e0 == 0) {
        float* sd = ksump + ((long)chunk * 64 + bh) * 64 + d0;
        #pragma unroll
        for (int d = 0; d < 4; ++d) sd[d] = sks[d];
    }
}

// ---------------------------------------------------------------------------
// Reduce NCHUNK partials -> kvb (bf16) and ksumf (f32). Grid: 64 blocks.
// ---------------------------------------------------------------------------
__global__ __launch_bounds__(256) void kv_reduce(const float* __restrict__ kvp,
                                                 const float* __restrict__ ksump,
                                                 ushort_t* __restrict__ kvb,
                                                 float* __restrict__ ksumf)
{
    const int bh = blockIdx.x;
    const int t = threadIdx.x;
    const long base = (long)bh * 4096 + t * 16;
    f32x4 s[4] = {};
    #pragma unroll 4
    for (int c = 0; c < NCHUNK; ++c) {
        const float* src = kvp + (long)c * 64 * 4096 + base;
        #pragma unroll
        for (int j = 0; j < 4; ++j) s[j] += *(const f32x4*)(src + j * 4);
    }
    short8 o0, o1;
    #pragma unroll
    for (int j = 0; j < 4; ++j) {
        o0[j]     = (short)f2bf(s[0][j]); o0[4 + j] = (short)f2bf(s[1][j]);
        o1[j]     = (short)f2bf(s[2][j]); o1[4 + j] = (short)f2bf(s[3][j]);
    }
    *(short8*)(kvb + base)     = o0;
    *(short8*)(kvb + base + 8) = o1;

    if (t < 64) {
        float ss = 0.f;
        #pragma unroll
        for (int c = 0; c < NCHUNK; ++c) ss += ksump[(long)c * 64 * 64 + bh * 64 + t];
        ksumf[bh * 64 + t] = ss;
    }
}

// ---------------------------------------------------------------------------
// num = phi(q) @ kvT^T ; denom = phi(q) . ksum ; O = num/(denom+1e-6), bf16.
// ---------------------------------------------------------------------------
__global__ __launch_bounds__(256) void attn_out(const ushort_t* __restrict__ Qp,
                                                const ushort_t* __restrict__ kvb,
                                                const float* __restrict__ ksum,
                                                ushort_t* __restrict__ Op)
{
    __shared__ __align__(16) ushort_t Qs[128 * 64];
    __shared__ __align__(16) ushort_t KVs[64 * 64];
    __shared__ float kss[64];
    __shared__ float dnm[128];
    const int t = threadIdx.x;
    const int w = t >> 6, lane = t & 63;
    const int bh = blockIdx.x, mc = blockIdx.y;
    const int b = bh >> 4, h = bh & 15;
    const long base = ((long)b * SS + mc * 128) * EMBED + h * DHD;

    #pragma unroll
    for (int ro = 0; ro < 4; ++ro) {
        const int idx = ro * 256 + t;
        const int r = idx >> 3, c16 = idx & 7;
        gl2lds16(Qp + base + (long)r * EMBED + c16 * 8,
                 (char*)Qs + (ro * 256 + w * 64) * 16);
    }
    #pragma unroll
    for (int ro = 0; ro < 2; ++ro) {
        const int idx = ro * 256 + t;
        gl2lds16(kvb + (long)bh * 4096 + idx * 8,
                 (char*)KVs + (ro * 256 + w * 64) * 16);
    }
    if (t < 64) kss[t] = ksum[bh * 64 + t];
    __syncthreads();

    if (t < 128) {   // denominator per row
        float s = 0.f;
        const uint_t* qr = (const uint_t*)(Qs + t * 64);
        #pragma unroll
        for (int jj = 0; jj < 32; ++jj) {
            const uint_t u = qr[jj];
            union { uint_t i; float f; } lo, hi;
            lo.i = u << 16; hi.i = u & 0xffff0000u;
            s += lo.f * kss[2 * jj] + hi.f * kss[2 * jj + 1];
        }
        dnm[t] = s;
    }

    const int fr = lane & 15, kq = (lane >> 4) * 8;
    f32x4 acc[2][4] = {};
    #pragma unroll
    for (int ks = 0; ks < 2; ++ks) {
        short8 av[2], bv[4];
        #pragma unroll
        for (int mi = 0; mi < 2; ++mi)
            av[mi] = *(const short8*)&Qs[(w * 32 + mi * 16 + fr) * 64 + ks * 32 + kq];
        #pragma unroll
        for (int nf = 0; nf < 4; ++nf)
            bv[nf] = *(const short8*)&KVs[(nf * 16 + fr) * 64 + ks * 32 + kq];
        #pragma unroll
        for (int mi = 0; mi < 2; ++mi)
            #pragma unroll
            for (int nf = 0; nf < 4; ++nf)
                acc[mi][nf] = __builtin_amdgcn_mfma_f32_16x16x32_bf16(
                    av[mi], bv[nf], acc[mi][nf], 0, 0, 0);
    }
    __syncthreads();

    const int rj = (lane >> 4) * 4;
    #pragma unroll
    for (int mi = 0; mi < 2; ++mi) {
        #pragma unroll
        for (int nf = 0; nf < 4; ++nf) {
            #pragma unroll
            for (int j = 0; j < 4; ++j) {
                const int r = w * 32 + mi * 16 + rj + j;
                const int c = nf * 16 + fr;
                const float x = acc[mi][nf][j] / (dnm[r] + 1e-6f);
                Op[base + (long)r * EMBED + c] = f2bf(x);
            }
        }
    }
}

// ---------------------------------------------------------------------------
extern "C" void kernel_launch(void* const* d_in, const int* in_sizes, int n_in,
                              void* d_out, int out_size, void* d_ws, size_t ws_size,
                              hipStream_t stream)
{
    (void)in_sizes; (void)n_in; (void)out_size; (void)ws_size;
    const float* query = (const float*)d_in[0];
    const float* key_  = (const float*)d_in[1];
    const float* value = (const float*)d_in[2];
    const float* q_dw  = (const float*)d_in[3];
    const float* q_uw  = (const float*)d_in[4];
    const float* q_ub  = (const float*)d_in[5];
    const float* k_dw  = (const float*)d_in[6];
    const float* k_uw  = (const float*)d_in[7];
    const float* k_ub  = (const float*)d_in[8];
    const float* v_dw  = (const float*)d_in[9];
    const float* v_uw  = (const float*)d_in[10];
    const float* v_ub  = (const float*)d_in[11];
    const float* o_w   = (const float*)d_in[12];
    const float* o_b   = (const float*)d_in[13];

    char* ws = (char*)d_ws;
    size_t off = 0;
    auto alloc = [&](size_t bytes) -> void* {
        void* p = ws + off;
        off += (bytes + 255) & ~(size_t)255;
        return p;
    };
    const size_t WSMALL = (size_t)RANK * EMBED;   // 524288
    ushort_t* bw_qd = (ushort_t*)alloc(WSMALL * 2);
    ushort_t* bw_qu = (ushort_t*)alloc(WSMALL * 2);
    ushort_t* bw_kd = (ushort_t*)alloc(WSMALL * 2);
    ushort_t* bw_ku = (ushort_t*)alloc(WSMALL * 2);
    ushort_t* bw_vd = (ushort_t*)alloc(WSMALL * 2);
    ushort_t* bw_vu = (ushort_t*)alloc(WSMALL * 2);
    ushort_t* bw_o  = (ushort_t*)alloc((size_t)EMBED * EMBED * 2);
    ushort_t* PQ    = (ushort_t*)alloc((size_t)MM * EMBED * 2);   // 33.55 MB
    ushort_t* PK    = (ushort_t*)alloc((size_t)MM * EMBED * 2);
    ushort_t* PV    = (ushort_t*)alloc((size_t)MM * EMBED * 2);
    ushort_t* Y1q   = (ushort_t*)alloc((size_t)MM * RANK * 2);    // 16.78 MB
    ushort_t* Y1k   = (ushort_t*)alloc((size_t)MM * RANK * 2);
    ushort_t* Y1v   = (ushort_t*)alloc((size_t)MM * RANK * 2);
    float*    ksump = (float*)alloc((size_t)NCHUNK * 64 * 64 * 4);
    float*    ksumf = (float*)alloc((size_t)64 * 64 * 4);
    ushort_t* kvb   = (ushort_t*)alloc((size_t)64 * 64 * 64 * 2);

    // Aliases (lifetime-disjoint):
    //  kvp (16,777,216 B) reuses Y1q (dead after up-proj).
    //  O (33.55 MB) reuses Y1k+Y1v (contiguous 2x16,777,216 B, 256-aligned).
    float*    kvp = (float*)Y1q;
    ushort_t* O   = Y1k;

    const dim3 blk(256);

    // 7 weight conversions in one dispatch (activations convert in-GEMM now)
    cvt_weights<<<dim3(EMBED * EMBED / 1024, 7), blk, 0, stream>>>(
        q_dw, q_uw, k_dw, k_uw, v_dw, v_uw, o_w,
        bw_qd, bw_qu, bw_kd, bw_ku, bw_vd, bw_vu, bw_o);

    // 3 down-projections, fused fp32->bf16 A staging
    gemm_dn<<<dim3(MM / 128 * (RANK / 128), 1, 3), blk, 0, stream>>>(
        query, key_, value,
        bw_qd, bw_kd, bw_vd,
        Y1q, Y1k, Y1v,
        RANK, EMBED, RANK / 128);

    // 3 up-projections: z=0 q (elu+1), z=1 k (elu+1), z=2 v (bias only)
    gemm_bt<2><<<dim3(MM / 128 * (EMBED / 128), 1, 3), blk, 0, stream>>>(
        Y1q, Y1k, Y1v,
        bw_qu, bw_ku, bw_vu,
        q_ub, k_ub, v_ub,
        PQ, PK, PV,
        EMBED, RANK, EMBED / 128);

    kv_stats<<<dim3(64, NCHUNK), blk, 0, stream>>>(PK, PV, kvp, ksump);
    kv_reduce<<<dim3(64), blk, 0, stream>>>(kvp, ksump, kvb, ksumf);
    attn_out<<<dim3(64, 32), blk, 0, stream>>>(PQ, kvb, ksumf, O);

    // output projection (fp32 out)
    gemm_bt<3><<<dim3(MM / 128 * (EMBED / 128), 1, 1), blk, 0, stream>>>(
        O, nullptr, nullptr,
        bw_o, nullptr, nullptr,
        o_b, nullptr, nullptr,
        d_out, nullptr, nullptr,
        EMBED, EMBED, EMBED / 128);
}

// Round 10
// 299.591 us; speedup vs baseline: 1.1346x; 1.0631x over previous
//
#include <hip/hip_runtime.h>
#include <hip/hip_bf16.h>

typedef unsigned short ushort_t;
typedef unsigned int uint_t;
typedef __attribute__((ext_vector_type(8))) short short8;
typedef __attribute__((ext_vector_type(4))) float f32x4;
typedef __attribute__((ext_vector_type(2))) float f32x2;

#define EMBED 1024
#define RANK  512
#define BB    4
#define SS    4096
#define HH    16
#define DHD   64
#define MM    (BB*SS)   // 16384 rows
#define NCHUNK 16       // kv_stats n-parallelism (256 rows per chunk)

__device__ __forceinline__ float bf2f(ushort_t u) {
    union { uint_t i; float f; } v; v.i = ((uint_t)u) << 16; return v.f;
}
__device__ __forceinline__ float asf(uint_t u) {
    union { uint_t i; float f; } v; v.i = u; return v.f;
}
__device__ __forceinline__ ushort_t f2bf(float f) {
    union { float f; uint_t i; } v; v.f = f;
    uint_t r = v.i + 0x7FFFu + ((v.i >> 16) & 1u);   // RNE
    return (ushort_t)(r >> 16);
}
// async global->LDS, 16B per lane; LDS dest must be wave-uniform base (+lane*16 in HW)
__device__ __forceinline__ void gl2lds16(const void* g, void* l) {
    __builtin_amdgcn_global_load_lds((const __attribute__((address_space(1))) void*)g,
                                     (__attribute__((address_space(3))) void*)l,
                                     16, 0, 0);
}

// ---------------------------------------------------------------------------
// NT-GEMM: C[M,N] = A[M,K] * B[N,K]^T (+ epilogue). 128x128 tile, BK=32,
// 256 threads = 4 waves, each wave a 64x64 quadrant (4x4 frags of 16x16x32).
// EXACT r6 configuration (measured local optimum, 3 blocks/CU):
// T4 counted-vmcnt pipeline, ring-3 / 2-step lookahead: prologue stages
// tiles 0,1; per iter: s_waitcnt vmcnt(4) (never 0 until tail) -> raw
// s_barrier -> STAGE(ti+2) -> ds_read+MFMA.
// T2 LDS swizzle (both-sides, rule #21): rows are 64B = 4x16B slots;
// slot' = slot ^ ((row>>1)&3), applied via pre-swizzled GLOBAL source column
// (LDS dest stays linear for global_load_lds) and matching swizzled ds_read.
// Coalesced bf16 epilogue: C tile staged in LDS at stride 136, then short8
// stores (256B contiguous per 16-lane group). fp32 (EPI 3) stores direct.
// Up to 3 independent GEMMs per dispatch via blockIdx.z (same N,K).
// Bijective XCD swizzle: each XCD owns a contiguous run of row-panels.
// EPI: 0 = none (bf16), 2 = +bias, elu+1 for z<2 / bias for z==2 (bf16),
//      3 = +bias (fp32 out).
// ---------------------------------------------------------------------------
template<int EPI>
__global__ __launch_bounds__(256) void gemm_bt(
    const ushort_t* __restrict__ A0, const ushort_t* __restrict__ A1, const ushort_t* __restrict__ A2,
    const ushort_t* __restrict__ B0, const ushort_t* __restrict__ B1, const ushort_t* __restrict__ B2,
    const float* __restrict__ bias0, const float* __restrict__ bias1, const float* __restrict__ bias2,
    void* __restrict__ C0, void* __restrict__ C1, void* __restrict__ C2,
    int N, int K, int nbx)
{
    // LDS ring-3: A bufs 8KB @ 0/8K/16K; B bufs @ 24K/32K/40K.
    // Epilogue C tile (128x136 bf16 = 34.8KB) reuses the front.
    __shared__ __align__(16) char lds_raw[49152];

    const int z = blockIdx.z;
    const ushort_t* Ab   = (z == 0) ? A0 : (z == 1) ? A1 : A2;
    const ushort_t* Bm   = (z == 0) ? B0 : (z == 1) ? B1 : B2;
    const float*    bias = (z == 0) ? bias0 : (z == 1) ? bias1 : bias2;
    void*           Cv   = (z == 0) ? C0 : (z == 1) ? C1 : C2;

    const int cpx = gridDim.x >> 3;
    const int bid = blockIdx.x;
    const int wg  = (bid & 7) * cpx + (bid >> 3);
    const long m0 = (long)(wg / nbx) * 128;
    const long n0 = (long)(wg % nbx) * 128;

    const int t = threadIdx.x;
    const int lane = t & 63;
    const int w = t >> 6;
    const int wr = (w >> 1) * 64;
    const int wc = (w & 1) * 64;
    const int fr = lane & 15;
    const int kq = (lane >> 4) * 8;

    const int srow = t >> 2;          // 0..63
    const int scol = ((t & 3) ^ ((srow >> 1) & 3)) * 8;
    const int kqs = (((kq >> 3) ^ ((fr >> 1) & 3))) * 8;

    auto STAGE = [&](int k0, int buf) {
        char* Ad = lds_raw + buf * 8192;
        char* Bd = lds_raw + 24576 + buf * 8192;
        #pragma unroll
        for (int ro = 0; ro < 2; ++ro) {
            const int row = ro * 64 + srow;
            gl2lds16(Ab + (m0 + row) * (long)K + k0 + scol, Ad + (ro * 256 + w * 64) * 16);
            gl2lds16(Bm + (n0 + row) * (long)K + k0 + scol, Bd + (ro * 256 + w * 64) * 16);
        }
    };

    f32x4 acc[4][4] = {};
    const int nt = K >> 5;

    STAGE(0, 0);
    STAGE(32, 1);

    int cur = 0;
    for (int ti = 0; ti < nt; ++ti) {
        if (ti + 1 < nt) { asm volatile("s_waitcnt vmcnt(4)" ::: "memory"); }
        else             { asm volatile("s_waitcnt vmcnt(0)" ::: "memory"); }
        __builtin_amdgcn_sched_barrier(0);
        __builtin_amdgcn_s_barrier();          // publish buf[cur]
        __builtin_amdgcn_sched_barrier(0);

        int nb = cur + 2; if (nb >= 3) nb -= 3;
        if (ti + 2 < nt) STAGE((ti + 2) << 5, nb);

        const ushort_t* Asc = (const ushort_t*)(lds_raw + cur * 8192);
        const ushort_t* Bsc = (const ushort_t*)(lds_raw + 24576 + cur * 8192);
        short8 av[4], bv[4];
        #pragma unroll
        for (int mi = 0; mi < 4; ++mi)
            av[mi] = *(const short8*)&Asc[(wr + mi * 16 + fr) * 32 + kqs];
        #pragma unroll
        for (int nf = 0; nf < 4; ++nf)
            bv[nf] = *(const short8*)&Bsc[(wc + nf * 16 + fr) * 32 + kqs];
        #pragma unroll
        for (int mi = 0; mi < 4; ++mi)
            #pragma unroll
            for (int nf = 0; nf < 4; ++nf)
                acc[mi][nf] = __builtin_amdgcn_mfma_f32_16x16x32_bf16(
                    av[mi], bv[nf], acc[mi][nf], 0, 0, 0);

        ++cur; if (cur == 3) cur = 0;
    }

    const int rj = (lane >> 4) * 4;
    if (EPI == 3) {
        float* Cf = (float*)Cv;
        __syncthreads();
        #pragma unroll
        for (int nf = 0; nf < 4; ++nf) {
            const long col = n0 + wc + nf * 16 + fr;
            const float bval = bias[col];
            #pragma unroll
            for (int mi = 0; mi < 4; ++mi)
                #pragma unroll
                for (int j = 0; j < 4; ++j)
                    Cf[(m0 + wr + mi * 16 + rj + j) * (long)N + col] = acc[mi][nf][j] + bval;
        }
    } else {
        ushort_t* Ct = (ushort_t*)lds_raw;     // 128x136 bf16 = 34.8KB
        __syncthreads();                        // K-loop LDS fully retired
        const bool do_elu = (EPI == 2) && (z < 2);
        #pragma unroll
        for (int nf = 0; nf < 4; ++nf) {
            const int coll = wc + nf * 16 + fr;
            const float bval = (EPI >= 2) ? bias[n0 + coll] : 0.0f;
            #pragma unroll
            for (int mi = 0; mi < 4; ++mi) {
                #pragma unroll
                for (int j = 0; j < 4; ++j) {
                    float x = acc[mi][nf][j];
                    if (EPI >= 2) x += bval;
                    if (do_elu) x = (x > 0.0f) ? (x + 1.0f) : __expf(x);
                    Ct[(wr + mi * 16 + rj + j) * 136 + coll] = f2bf(x);
                }
            }
        }
        __syncthreads();
        ushort_t* Cb = (ushort_t*)Cv;
        #pragma unroll
        for (int it = 0; it < 8; ++it) {
            const int idx = it * 256 + t;
            const int r   = idx >> 4;
            const int c8  = (idx & 15) * 8;
            short8 vv = *(const short8*)&Ct[r * 136 + c8];
            *(short8*)(Cb + (m0 + r) * (long)N + n0 + c8) = vv;
        }
    }
}

// ---------------------------------------------------------------------------
// Activation convert: fp32 -> bf16, 8 elems/thread. blockIdx.y picks q/k/v.
// ---------------------------------------------------------------------------
__global__ __launch_bounds__(256) void cvt_act(const float* __restrict__ q,
                                               const float* __restrict__ k,
                                               const float* __restrict__ v,
                                               ushort_t* __restrict__ qo,
                                               ushort_t* __restrict__ ko,
                                               ushort_t* __restrict__ vo)
{
    const int zz = blockIdx.y;
    const float* src = (zz == 0) ? q : (zz == 1) ? k : v;
    ushort_t*    dst = (zz == 0) ? qo : (zz == 1) ? ko : vo;
    const long i = ((long)blockIdx.x * 256 + threadIdx.x) * 8;
    f32x4 f0 = *(const f32x4*)(src + i);
    f32x4 f1 = *(const f32x4*)(src + i + 4);
    short8 h;
    h[0] = (short)f2bf(f0[0]); h[1] = (short)f2bf(f0[1]);
    h[2] = (short)f2bf(f0[2]); h[3] = (short)f2bf(f0[3]);
    h[4] = (short)f2bf(f1[0]); h[5] = (short)f2bf(f1[1]);
    h[6] = (short)f2bf(f1[2]); h[7] = (short)f2bf(f1[3]);
    *(short8*)(dst + i) = h;
}

// ---------------------------------------------------------------------------
// All 7 weight conversions in one dispatch. blockIdx.y selects the weight.
// ---------------------------------------------------------------------------
__global__ __launch_bounds__(256) void cvt_weights(
    const float* __restrict__ s0, const float* __restrict__ s1,
    const float* __restrict__ s2, const float* __restrict__ s3,
    const float* __restrict__ s4, const float* __restrict__ s5,
    const float* __restrict__ s6,
    ushort_t* __restrict__ d0, ushort_t* __restrict__ d1,
    ushort_t* __restrict__ d2, ushort_t* __restrict__ d3,
    ushort_t* __restrict__ d4, ushort_t* __restrict__ d5,
    ushort_t* __restrict__ d6)
{
    const int y = blockIdx.y;
    const float* src; ushort_t* dst; int n;
    switch (y) {
        case 0: src = s0; dst = d0; n = RANK * EMBED; break;
        case 1: src = s1; dst = d1; n = RANK * EMBED; break;
        case 2: src = s2; dst = d2; n = RANK * EMBED; break;
        case 3: src = s3; dst = d3; n = RANK * EMBED; break;
        case 4: src = s4; dst = d4; n = RANK * EMBED; break;
        case 5: src = s5; dst = d5; n = RANK * EMBED; break;
        default: src = s6; dst = d6; n = EMBED * EMBED; break;
    }
    const int i = (blockIdx.x * 256 + threadIdx.x) * 4;
    if (i < n) {
        f32x4 f = *(const f32x4*)(src + i);
        typedef __attribute__((ext_vector_type(4))) short short4v;
        short4v h;
        h[0] = (short)f2bf(f[0]); h[1] = (short)f2bf(f[1]);
        h[2] = (short)f2bf(f[2]); h[3] = (short)f2bf(f[3]);
        *(short4v*)(dst + i) = h;
    }
}

// ---------------------------------------------------------------------------
// Per-head partial stats over a 256-row n-chunk:
//   kvp[chunk][bh][e][d] = sum_n V[n,e]*K[n,d];  ksump[chunk][bh][d] = sum_n K[n,d]
// Grid: (64 bh, NCHUNK). 256 threads; thread owns 4 e x 4 d register tile.
// PACKED-FMA version: accumulators are f32x2 pairs so the compiler can emit
// v_pk_fma_f32 (2-wide) — kv_stats was at the SCALAR v_fma roofline (~21us
// for 1.07e9 MACs at 103 TF); packed math halves the FMA instruction count.
// Per-element arithmetic identical (same order) -> bit-identical output.
// ---------------------------------------------------------------------------
__global__ __launch_bounds__(256) void kv_stats(const ushort_t* __restrict__ Kp,
                                                const ushort_t* __restrict__ Vp,
                                                float* __restrict__ kvp,
                                                float* __restrict__ ksump)
{
    __shared__ __align__(16) ushort_t Ks[64 * 64];
    __shared__ __align__(16) ushort_t Vs[64 * 64];
    const int t = threadIdx.x;
    const int w = t >> 6;
    const int bh = blockIdx.x;
    const int chunk = blockIdx.y;
    const int b = bh >> 4, h = bh & 15;
    const int d0 = (t & 15) * 4;
    const int e0 = (t >> 4) * 4;
    f32x2 acc2[4][2] = {};
    f32x2 sks2[2] = {};
    const long hbase = ((long)b * SS) * EMBED + h * DHD;

    for (int sub = 0; sub < 4; ++sub) {
        const int n00 = chunk * 256 + sub * 64;
        #pragma unroll
        for (int ro = 0; ro < 2; ++ro) {
            const int idx = ro * 256 + t;
            const int r = idx >> 3, c16 = idx & 7;
            const long g = hbase + (long)(n00 + r) * EMBED + c16 * 8;
            gl2lds16(Kp + g, (char*)Ks + (ro * 256 + w * 64) * 16);
            gl2lds16(Vp + g, (char*)Vs + (ro * 256 + w * 64) * 16);
        }
        __syncthreads();
        #pragma unroll 8
        for (int n = 0; n < 64; ++n) {
            const uint_t* kr = (const uint_t*)(Ks + n * 64 + d0);
            const uint_t* vr = (const uint_t*)(Vs + n * 64 + e0);
            const uint_t k01 = kr[0], k23 = kr[1];
            const uint_t v01 = vr[0], v23 = vr[1];
            f32x2 kd0, kd1;
            kd0[0] = asf(k01 << 16); kd0[1] = asf(k01 & 0xffff0000u);
            kd1[0] = asf(k23 << 16); kd1[1] = asf(k23 & 0xffff0000u);
            float ve[4];
            ve[0] = asf(v01 << 16); ve[1] = asf(v01 & 0xffff0000u);
            ve[2] = asf(v23 << 16); ve[3] = asf(v23 & 0xffff0000u);
            #pragma unroll
            for (int e = 0; e < 4; ++e) {
                f32x2 vb; vb[0] = ve[e]; vb[1] = ve[e];
                acc2[e][0] += vb * kd0;
                acc2[e][1] += vb * kd1;
            }
            if (e0 == 0) { sks2[0] += kd0; sks2[1] += kd1; }
        }
        __syncthreads();
    }

    float* dst = kvp + ((long)chunk * 64 + bh) * 4096;
    #pragma unroll
    for (int e = 0; e < 4; ++e) {
        f32x4 vv;
        vv[0] = acc2[e][0][0]; vv[1] = acc2[e][0][1];
        vv[2] = acc2[e][1][0]; vv[3] = acc2[e][1][1];
        *(f32x4*)(dst + (e0 + e) * 64 + d0) = vv;
    }
    if (e0 == 0) {
        float* sd = ksump + ((long)chunk * 64 + bh) * 64 + d0;
        sd[0] = sks2[0][0]; sd[1] = sks2[0][1];
        sd[2] = sks2[1][0]; sd[3] = sks2[1][1];
    }
}

// ---------------------------------------------------------------------------
// Reduce NCHUNK partials -> kvb (bf16) and ksumf (f32). Grid: 64 blocks.
// ---------------------------------------------------------------------------
__global__ __launch_bounds__(256) void kv_reduce(const float* __restrict__ kvp,
                                                 const float* __restrict__ ksump,
                                                 ushort_t* __restrict__ kvb,
                                                 float* __restrict__ ksumf)
{
    const int bh = blockIdx.x;
    const int t = threadIdx.x;
    const long base = (long)bh * 4096 + t * 16;
    f32x4 s[4] = {};
    #pragma unroll 4
    for (int c = 0; c < NCHUNK; ++c) {
        const float* src = kvp + (long)c * 64 * 4096 + base;
        #pragma unroll
        for (int j = 0; j < 4; ++j) s[j] += *(const f32x4*)(src + j * 4);
    }
    short8 o0, o1;
    #pragma unroll
    for (int j = 0; j < 4; ++j) {
        o0[j]     = (short)f2bf(s[0][j]); o0[4 + j] = (short)f2bf(s[1][j]);
        o1[j]     = (short)f2bf(s[2][j]); o1[4 + j] = (short)f2bf(s[3][j]);
    }
    *(short8*)(kvb + base)     = o0;
    *(short8*)(kvb + base + 8) = o1;

    if (t < 64) {
        float ss = 0.f;
        #pragma unroll
        for (int c = 0; c < NCHUNK; ++c) ss += ksump[(long)c * 64 * 64 + bh * 64 + t];
        ksumf[bh * 64 + t] = ss;
    }
}

// ---------------------------------------------------------------------------
// num = phi(q) @ kvT^T ; denom = phi(q) . ksum ; O = num/(denom+1e-6), bf16.
// Grid: (64 bh, 32 chunks of 128 rows). 4 waves, wave w owns rows w*32..+32.
// ---------------------------------------------------------------------------
__global__ __launch_bounds__(256) void attn_out(const ushort_t* __restrict__ Qp,
                                                const ushort_t* __restrict__ kvb,
                                                const float* __restrict__ ksum,
                                                ushort_t* __restrict__ Op)
{
    __shared__ __align__(16) ushort_t Qs[128 * 64];
    __shared__ __align__(16) ushort_t KVs[64 * 64];
    __shared__ float kss[64];
    __shared__ float dnm[128];
    const int t = threadIdx.x;
    const int w = t >> 6, lane = t & 63;
    const int bh = blockIdx.x, mc = blockIdx.y;
    const int b = bh >> 4, h = bh & 15;
    const long base = ((long)b * SS + mc * 128) * EMBED + h * DHD;

    #pragma unroll
    for (int ro = 0; ro < 4; ++ro) {
        const int idx = ro * 256 + t;
        const int r = idx >> 3, c16 = idx & 7;
        gl2lds16(Qp + base + (long)r * EMBED + c16 * 8,
                 (char*)Qs + (ro * 256 + w * 64) * 16);
    }
    #pragma unroll
    for (int ro = 0; ro < 2; ++ro) {
        const int idx = ro * 256 + t;
        gl2lds16(kvb + (long)bh * 4096 + idx * 8,
                 (char*)KVs + (ro * 256 + w * 64) * 16);
    }
    if (t < 64) kss[t] = ksum[bh * 64 + t];
    __syncthreads();

    if (t < 128) {   // denominator per row
        float s = 0.f;
        const uint_t* qr = (const uint_t*)(Qs + t * 64);
        #pragma unroll
        for (int jj = 0; jj < 32; ++jj) {
            const uint_t u = qr[jj];
            union { uint_t i; float f; } lo, hi;
            lo.i = u << 16; hi.i = u & 0xffff0000u;
            s += lo.f * kss[2 * jj] + hi.f * kss[2 * jj + 1];
        }
        dnm[t] = s;
    }

    const int fr = lane & 15, kq = (lane >> 4) * 8;
    f32x4 acc[2][4] = {};
    #pragma unroll
    for (int ks = 0; ks < 2; ++ks) {
        short8 av[2], bv[4];
        #pragma unroll
        for (int mi = 0; mi < 2; ++mi)
            av[mi] = *(const short8*)&Qs[(w * 32 + mi * 16 + fr) * 64 + ks * 32 + kq];
        #pragma unroll
        for (int nf = 0; nf < 4; ++nf)
            bv[nf] = *(const short8*)&KVs[(nf * 16 + fr) * 64 + ks * 32 + kq];
        #pragma unroll
        for (int mi = 0; mi < 2; ++mi)
            #pragma unroll
            for (int nf = 0; nf < 4; ++nf)
                acc[mi][nf] = __builtin_amdgcn_mfma_f32_16x16x32_bf16(
                    av[mi], bv[nf], acc[mi][nf], 0, 0, 0);
    }
    __syncthreads();

    const int rj = (lane >> 4) * 4;
    #pragma unroll
    for (int mi = 0; mi < 2; ++mi) {
        #pragma unroll
        for (int nf = 0; nf < 4; ++nf) {
            #pragma unroll
            for (int j = 0; j < 4; ++j) {
                const int r = w * 32 + mi * 16 + rj + j;
                const int c = nf * 16 + fr;
                const float x = acc[mi][nf][j] / (dnm[r] + 1e-6f);
                Op[base + (long)r * EMBED + c] = f2bf(x);
            }
        }
    }
}

// ---------------------------------------------------------------------------
extern "C" void kernel_launch(void* const* d_in, const int* in_sizes, int n_in,
                              void* d_out, int out_size, void* d_ws, size_t ws_size,
                              hipStream_t stream)
{
    (void)in_sizes; (void)n_in; (void)out_size; (void)ws_size;
    const float* query = (const float*)d_in[0];
    const float* key_  = (const float*)d_in[1];
    const float* value = (const float*)d_in[2];
    const float* q_dw  = (const float*)d_in[3];
    const float* q_uw  = (const float*)d_in[4];
    const float* q_ub  = (const float*)d_in[5];
    const float* k_dw  = (const float*)d_in[6];
    const float* k_uw  = (const float*)d_in[7];
    const float* k_ub  = (const float*)d_in[8];
    const float* v_dw  = (const float*)d_in[9];
    const float* v_uw  = (const float*)d_in[10];
    const float* v_ub  = (const float*)d_in[11];
    const float* o_w   = (const float*)d_in[12];
    const float* o_b   = (const float*)d_in[13];

    char* ws = (char*)d_ws;
    size_t off = 0;
    auto alloc = [&](size_t bytes) -> void* {
        void* p = ws + off;
        off += (bytes + 255) & ~(size_t)255;
        return p;
    };
    const size_t WSMALL = (size_t)RANK * EMBED;   // 524288
    ushort_t* bw_qd = (ushort_t*)alloc(WSMALL * 2);
    ushort_t* bw_qu = (ushort_t*)alloc(WSMALL * 2);
    ushort_t* bw_kd = (ushort_t*)alloc(WSMALL * 2);
    ushort_t* bw_ku = (ushort_t*)alloc(WSMALL * 2);
    ushort_t* bw_vd = (ushort_t*)alloc(WSMALL * 2);
    ushort_t* bw_vu = (ushort_t*)alloc(WSMALL * 2);
    ushort_t* bw_o  = (ushort_t*)alloc((size_t)EMBED * EMBED * 2);
    ushort_t* Qb    = (ushort_t*)alloc((size_t)MM * EMBED * 2);   // 33.55 MB
    ushort_t* Kb    = (ushort_t*)alloc((size_t)MM * EMBED * 2);
    ushort_t* Vb    = (ushort_t*)alloc((size_t)MM * EMBED * 2);
    ushort_t* Y1q   = (ushort_t*)alloc((size_t)MM * RANK * 2);    // 16.78 MB
    ushort_t* Y1k   = (ushort_t*)alloc((size_t)MM * RANK * 2);
    ushort_t* Y1v   = (ushort_t*)alloc((size_t)MM * RANK * 2);
    float*    ksump = (float*)alloc((size_t)NCHUNK * 64 * 64 * 4);
    float*    ksumf = (float*)alloc((size_t)64 * 64 * 4);
    ushort_t* kvb   = (ushort_t*)alloc((size_t)64 * 64 * 64 * 2);

    // Aliases (lifetime-disjoint):
    //  PQ/PK/PV reuse Qb/Kb/Vb (dead after down-proj).
    //  kvp (NCHUNK*64*4096*4 = 16,777,216 B) reuses Y1q (dead after up-proj).
    //  O (33.55 MB) reuses Y1k+Y1v (contiguous 2x16,777,216 B, 256-aligned).
    ushort_t* PQ = Qb;
    ushort_t* PK = Kb;
    ushort_t* PV = Vb;
    float*    kvp = (float*)Y1q;
    ushort_t* O   = Y1k;

    const dim3 blk(256);

    // converts: QKV activations (8 elems/thread) + 7 weights
    cvt_act<<<dim3((size_t)MM * EMBED / 2048, 3), blk, 0, stream>>>(
        query, key_, value, Qb, Kb, Vb);
    cvt_weights<<<dim3(EMBED * EMBED / 1024, 7), blk, 0, stream>>>(
        q_dw, q_uw, k_dw, k_uw, v_dw, v_uw, o_w,
        bw_qd, bw_qu, bw_kd, bw_ku, bw_vd, bw_vu, bw_o);

    // 3 down-projections in one dispatch (pure bf16)
    gemm_bt<0><<<dim3(MM / 128 * (RANK / 128), 1, 3), blk, 0, stream>>>(
        Qb, Kb, Vb,
        bw_qd, bw_kd, bw_vd,
        nullptr, nullptr, nullptr,
        Y1q, Y1k, Y1v,
        RANK, EMBED, RANK / 128);

    // 3 up-projections: z=0 q (elu+1), z=1 k (elu+1), z=2 v (bias only)
    gemm_bt<2><<<dim3(MM / 128 * (EMBED / 128), 1, 3), blk, 0, stream>>>(
        Y1q, Y1k, Y1v,
        bw_qu, bw_ku, bw_vu,
        q_ub, k_ub, v_ub,
        PQ, PK, PV,
        EMBED, RANK, EMBED / 128);

    kv_stats<<<dim3(64, NCHUNK), blk, 0, stream>>>(PK, PV, kvp, ksump);
    kv_reduce<<<dim3(64), blk, 0, stream>>>(kvp, ksump, kvb, ksumf);
    attn_out<<<dim3(64, 32), blk, 0, stream>>>(PQ, kvb, ksumf, O);

    // output projection (fp32 out)
    gemm_bt<3><<<dim3(MM / 128 * (EMBED / 128), 1, 1), blk, 0, stream>>>(
        O, nullptr, nullptr,
        bw_o, nullptr, nullptr,
        o_b, nullptr, nullptr,
        d_out, nullptr, nullptr,
        EMBED, EMBED, EMBED / 128);
}